// Round 9
// baseline (326.610 us; speedup 1.0000x reference)
//
#include <hip/hip_runtime.h>
#include <stdint.h>

#define N_NODES 100000
#define N_EDGES 1600000
#define D_INF   128
#define D_HID   64
#define D_LAT   32

typedef __attribute__((ext_vector_type(8))) short bf16x8;
typedef __attribute__((ext_vector_type(4))) float f32x4;
typedef __attribute__((ext_vector_type(8))) unsigned short u16x8;

__device__ __forceinline__ unsigned short f2bf(float v) {
  union { float f; unsigned int u; } x; x.f = v;
  unsigned int u = x.u + 0x7FFF + ((x.u >> 16) & 1);   // RNE
  return (unsigned short)(u >> 16);
}
__device__ __forceinline__ float bf2f(unsigned short h) {
  union { unsigned int u; float f; } x; x.u = ((unsigned int)h) << 16;
  return x.f;
}

// ---------------- binned CSR build ----------------

#define NBKT      196    // ceil(100000 / 512)
#define BKT_SHIFT 9      // 512 nodes per bucket
#define BKT_CAP   9216   // fixed region capacity (mean 8192, sigma ~90 -> 11σ)
#define EPB       2048   // edges per pass-A block
#define ABLOCKS   782    // ceil(1600000 / 2048)

__global__ __launch_bounds__(256) void k_binA(const int* __restrict__ esrc,
                                              const int* __restrict__ edst,
                                              int* __restrict__ bkcnt,
                                              int* __restrict__ stage) {
  __shared__ int cnt[NBKT];
  __shared__ int sc[256];
  __shared__ int garel[NBKT];
  __shared__ int pos[NBKT];
  __shared__ __align__(16) int2 stg[EPB];   // 16 KB
  int t = threadIdx.x;
  int e0 = blockIdx.x * EPB;

  for (int i = t; i < NBKT; i += 256) cnt[i] = 0;
  __syncthreads();

  int ds[8], ss[8];
  const int4* s4 = (const int4*)esrc;
  const int4* d4 = (const int4*)edst;
#pragma unroll
  for (int i = 0; i < 2; i++) {
    int idx4 = (e0 >> 2) + i * 256 + t;
    int4 dd = make_int4(-1, -1, -1, -1);
    int4 sv = make_int4(0, 0, 0, 0);
    if (idx4 < N_EDGES / 4) { dd = d4[idx4]; sv = s4[idx4]; }
    ds[i*4+0] = dd.x; ds[i*4+1] = dd.y; ds[i*4+2] = dd.z; ds[i*4+3] = dd.w;
    ss[i*4+0] = sv.x; ss[i*4+1] = sv.y; ss[i*4+2] = sv.z; ss[i*4+3] = sv.w;
  }
#pragma unroll
  for (int j = 0; j < 8; j++)
    if (ds[j] >= 0) atomicAdd(&cnt[ds[j] >> BKT_SHIFT], 1);
  __syncthreads();

  int c = (t < NBKT) ? cnt[t] : 0;
  sc[t] = c;
  __syncthreads();
  int incl = c;
#pragma unroll
  for (int off = 1; off < 256; off <<= 1) {
    int x = (t >= off) ? sc[t - off] : 0;
    __syncthreads();
    incl += x;
    sc[t] = incl;
    __syncthreads();
  }
  if (t < NBKT) {
    int lb = incl - c;
    int gb = 0;
    if (c > 0) gb = t * BKT_CAP + atomicAdd(&bkcnt[t], c);
    garel[t] = gb - lb;
    pos[t]   = lb;
  }
  __syncthreads();

#pragma unroll
  for (int j = 0; j < 8; j++) {
    if (ds[j] >= 0) {
      int b  = ds[j] >> BKT_SHIFT;
      int lp = atomicAdd(&pos[b], 1);
      stg[lp] = make_int2(ss[j], ds[j]);
    }
  }
  __syncthreads();

  int nval = N_EDGES - e0; if (nval > EPB) nval = EPB;
  for (int i = t; i < nval; i += 256) {
    int2 e = stg[i];
    stage[garel[e.y >> BKT_SHIFT] + i] = (e.x << BKT_SHIFT) | (e.y & 511);
  }
}

// one block per bucket: histogram + scan + scatter, all bucket-local
__global__ __launch_bounds__(1024) void k_csr(const int* __restrict__ stage,
                                              const int* __restrict__ bkcnt,
                                              int* __restrict__ beg,
                                              int* __restrict__ cnt,
                                              float* __restrict__ dinv,
                                              int* __restrict__ csr4) {
  __shared__ int hist[512];
  __shared__ int scan[512];
  int b = blockIdx.x, t = threadIdx.x;
  if (t < 512) hist[t] = 0;
  __syncthreads();
  int n = bkcnt[b];
  int nlo = b << BKT_SHIFT;
  const int* reg = stage + (size_t)b * BKT_CAP;
  for (int i = t; i < n; i += 1024)
    atomicAdd(&hist[reg[i] & 511], 1);
  __syncthreads();
  int v = (t < 512) ? hist[t] : 0;
  if (t < 512) scan[t] = v;
  __syncthreads();
  int incl = v;
#pragma unroll
  for (int off = 1; off < 512; off <<= 1) {
    int x = (t >= off && t < 512) ? scan[t - off] : 0;
    __syncthreads();
    if (t < 512) { incl += x; scan[t] = incl; }
    __syncthreads();
  }
  if (t < 512) {
    int loc = incl - v;
    int node = nlo + t;
    if (node < N_NODES) {
      beg[node]  = b * BKT_CAP + loc;
      cnt[node]  = v;
      dinv[node] = rsqrtf((float)(v + 1));
    }
    scan[t] = loc;
  }
  __syncthreads();
  int* c4 = csr4 + (size_t)b * BKT_CAP;
  for (int i = t; i < n; i += 1024) {
    int e = reg[i];
    int slot = atomicAdd(&scan[e & 511], 1);
    c4[slot] = e >> BKT_SHIFT;
  }
}

// ---------------- weight prep (block 4 zeroes bkcnt) ----------------

__global__ void k_prep_w(const float* __restrict__ W1, const float* __restrict__ W2,
                         const float* __restrict__ Wd1, const float* __restrict__ Wd2,
                         unsigned short* __restrict__ w1hi, unsigned short* __restrict__ w1lo,
                         unsigned short* __restrict__ w2hi, unsigned short* __restrict__ w2lo,
                         unsigned short* __restrict__ wd1hi, unsigned short* __restrict__ wd1lo,
                         unsigned short* __restrict__ wd2hi, unsigned short* __restrict__ wd2lo,
                         int* __restrict__ bkcnt) {
  if (blockIdx.x == 4) {
    if (threadIdx.x < NBKT) bkcnt[threadIdx.x] = 0;
    return;
  }
  const float* src; unsigned short *hi, *lo; int K, M;
  switch (blockIdx.x) {
    case 0:  src = W1;  hi = w1hi;  lo = w1lo;  K = 128; M = 64;  break;
    case 1:  src = W2;  hi = w2hi;  lo = w2lo;  K = 64;  M = 32;  break;
    case 2:  src = Wd1; hi = wd1hi; lo = wd1lo; K = 32;  M = 64;  break;
    default: src = Wd2; hi = wd2hi; lo = wd2lo; K = 64;  M = 128; break;
  }
  int KP = K + 8;
  for (int i = threadIdx.x; i < K * M; i += 256) {
    int k = i / M, c = i % M;
    float v = src[i];
    unsigned short h = f2bf(v);
    hi[c * KP + k] = h;
    lo[c * KP + k] = f2bf(v - bf2f(h));
  }
}

// ---------------- MFMA GEMM: Y[N,M] = (X[N,K] @ W[K,M]) * dinv[n], bf16 out --------

template<int NODES, int K, int M>
__global__ __launch_bounds__(256) void k_mfma_gemm(const float* __restrict__ X,
                                                   const unsigned short* __restrict__ Bhi,
                                                   const unsigned short* __restrict__ Blo,
                                                   const float* __restrict__ dinv,
                                                   unsigned short* __restrict__ Y16) {
  constexpr int KP     = K + 8;
  constexpr int NSTRIP = M / 16;
  constexpr int KSTEPS = K / 32;
  constexpr int MTW    = (NODES / 16) * NSTRIP / 4;
  __shared__ __align__(16) unsigned short Ahi[NODES * KP];
  __shared__ __align__(16) unsigned short Alo[NODES * KP];

  int t = threadIdx.x;
  int node0 = blockIdx.x * NODES;

  for (int i = t; i < NODES * K / 4; i += 256) {
    int n = i / (K / 4), f4 = i % (K / 4);
    float4 v = make_float4(0.f, 0.f, 0.f, 0.f);
    if (node0 + n < N_NODES) v = ((const float4*)(X + (size_t)(node0 + n) * K))[f4];
    int base = n * KP + f4 * 4;
    float vv[4] = {v.x, v.y, v.z, v.w};
#pragma unroll
    for (int j = 0; j < 4; j++) {
      unsigned short h = f2bf(vv[j]);
      Ahi[base + j] = h;
      Alo[base + j] = f2bf(vv[j] - bf2f(h));
    }
  }
  __syncthreads();

  int w = t >> 6, lane = t & 63;
  int quad = lane >> 4, r16 = lane & 15;
  int strip = w % NSTRIP;

  bf16x8 bh[KSTEPS], bl[KSTEPS];
  const unsigned short* bp = Bhi + (strip * 16 + r16) * KP + quad * 8;
  const unsigned short* bq = Blo + (strip * 16 + r16) * KP + quad * 8;
#pragma unroll
  for (int ks = 0; ks < KSTEPS; ks++) {
    bh[ks] = *(const bf16x8*)(bp + ks * 32);
    bl[ks] = *(const bf16x8*)(bq + ks * 32);
  }

#pragma unroll
  for (int c = 0; c < MTW; c++) {
    int mt = (w / NSTRIP) * MTW + c;
    f32x4 acc = {0.f, 0.f, 0.f, 0.f};
    const unsigned short* ap = &Ahi[(mt * 16 + r16) * KP + quad * 8];
    const unsigned short* aq = &Alo[(mt * 16 + r16) * KP + quad * 8];
#pragma unroll
    for (int ks = 0; ks < KSTEPS; ks++) {
      bf16x8 ah = *(const bf16x8*)(ap + ks * 32);
      bf16x8 al = *(const bf16x8*)(aq + ks * 32);
      acc = __builtin_amdgcn_mfma_f32_16x16x32_bf16(ah, bh[ks], acc, 0, 0, 0);
      acc = __builtin_amdgcn_mfma_f32_16x16x32_bf16(ah, bl[ks], acc, 0, 0, 0);
      acc = __builtin_amdgcn_mfma_f32_16x16x32_bf16(al, bh[ks], acc, 0, 0, 0);
    }
    int gn  = node0 + mt * 16 + quad * 4;
    int col = strip * 16 + r16;
#pragma unroll
    for (int r = 0; r < 4; r++) {
      if (gn + r < N_NODES)
        Y16[(size_t)(gn + r) * M + col] = f2bf(acc[r] * dinv[gn + r]);
    }
  }
}

// ---------------- fused agg1 (FEAT=64, relu) + GEMM2 (64x64 @ W2 -> 32) ----------
// Block = 4 waves = 64 nodes. Each wave aggregates 16 nodes sequentially,
// writing z1 rows bf16 hi/lo into LDS (identical decomposition to the old
// global staging), then the block does the 64x32 MFMA and writes h2'.

__global__ __launch_bounds__(256) void k_agg1_gemm2(
    const unsigned short* __restrict__ H16,
    const int* __restrict__ beg, const int* __restrict__ cnt,
    const int* __restrict__ csr4,
    const float* __restrict__ dinv, const float* __restrict__ bias,
    const unsigned short* __restrict__ B2hi, const unsigned short* __restrict__ B2lo,
    unsigned short* __restrict__ H2) {
  constexpr int KP = 72;   // 64+8
  __shared__ __align__(16) unsigned short Azhi[64 * KP];
  __shared__ __align__(16) unsigned short Azlo[64 * KP];
  int t = threadIdx.x, w = t >> 6, lane = t & 63;
  int node0 = blockIdx.x * 64;
  int g = lane >> 3, f8 = lane & 7;    // 8 lanes/edge, 8 edges/gather

  for (int it = 0; it < 16; ++it) {
    int row  = it * 4 + w;
    int node = node0 + row;
    float a0=0.f,a1=0.f,a2=0.f,a3=0.f,a4=0.f,a5=0.f,a6=0.f,a7=0.f;
    if (node < N_NODES) {
      int bg = beg[node], end = bg + cnt[node];
      for (int p = bg; p < end; p += 32) {
        int   sarr[4]; float marr[4]; u16x8 harr[4];
#pragma unroll
        for (int b4 = 0; b4 < 4; b4++) {
          int q = p + b4 * 8 + g;
          sarr[b4] = (q < end) ? csr4[q] : node;
          marr[b4] = (q < end) ? 1.f : 0.f;
        }
#pragma unroll
        for (int b4 = 0; b4 < 4; b4++)
          harr[b4] = *(const u16x8*)(H16 + (size_t)sarr[b4] * 64 + f8 * 8);
#pragma unroll
        for (int b4 = 0; b4 < 4; b4++) {
          float m = marr[b4]; u16x8 h = harr[b4];
          a0 += bf2f(h[0]) * m; a1 += bf2f(h[1]) * m;
          a2 += bf2f(h[2]) * m; a3 += bf2f(h[3]) * m;
          a4 += bf2f(h[4]) * m; a5 += bf2f(h[5]) * m;
          a6 += bf2f(h[6]) * m; a7 += bf2f(h[7]) * m;
        }
      }
#pragma unroll
      for (int off = 8; off < 64; off <<= 1) {
        a0 += __shfl_xor(a0, off, 64); a1 += __shfl_xor(a1, off, 64);
        a2 += __shfl_xor(a2, off, 64); a3 += __shfl_xor(a3, off, 64);
        a4 += __shfl_xor(a4, off, 64); a5 += __shfl_xor(a5, off, 64);
        a6 += __shfl_xor(a6, off, 64); a7 += __shfl_xor(a7, off, 64);
      }
    }
    if (g == 0) {
      float vals[8] = {0.f,0.f,0.f,0.f,0.f,0.f,0.f,0.f};
      if (node < N_NODES) {
        float di = dinv[node];
        u16x8 hs = *(const u16x8*)(H16 + (size_t)node * 64 + f8 * 8);
        float4 bv0 = *(const float4*)(bias + f8 * 8);
        float4 bv1 = *(const float4*)(bias + f8 * 8 + 4);
        vals[0] = fmaxf((a0 + bf2f(hs[0])) * di + bv0.x, 0.f);
        vals[1] = fmaxf((a1 + bf2f(hs[1])) * di + bv0.y, 0.f);
        vals[2] = fmaxf((a2 + bf2f(hs[2])) * di + bv0.z, 0.f);
        vals[3] = fmaxf((a3 + bf2f(hs[3])) * di + bv0.w, 0.f);
        vals[4] = fmaxf((a4 + bf2f(hs[4])) * di + bv1.x, 0.f);
        vals[5] = fmaxf((a5 + bf2f(hs[5])) * di + bv1.y, 0.f);
        vals[6] = fmaxf((a6 + bf2f(hs[6])) * di + bv1.z, 0.f);
        vals[7] = fmaxf((a7 + bf2f(hs[7])) * di + bv1.w, 0.f);
      }
      int base = row * KP + f8 * 8;
#pragma unroll
      for (int j = 0; j < 8; j++) {
        unsigned short h = f2bf(vals[j]);
        Azhi[base + j] = h;
        Azlo[base + j] = f2bf(vals[j] - bf2f(h));
      }
    }
  }
  __syncthreads();

  // GEMM: [64 rows x K=64] @ W2 -> [64 x 32], h2' = out * dinv
  int quad = lane >> 4, r16 = lane & 15;
  int strip = w & 1;
  const unsigned short* bp = B2hi + (strip * 16 + r16) * KP + quad * 8;
  const unsigned short* bq = B2lo + (strip * 16 + r16) * KP + quad * 8;
  bf16x8 bh0 = *(const bf16x8*)(bp);
  bf16x8 bh1 = *(const bf16x8*)(bp + 32);
  bf16x8 bl0 = *(const bf16x8*)(bq);
  bf16x8 bl1 = *(const bf16x8*)(bq + 32);
#pragma unroll
  for (int c = 0; c < 2; ++c) {
    int mt = (w >> 1) * 2 + c;
    const unsigned short* ap = &Azhi[(mt * 16 + r16) * KP + quad * 8];
    const unsigned short* aq = &Azlo[(mt * 16 + r16) * KP + quad * 8];
    bf16x8 ah0 = *(const bf16x8*)(ap);
    bf16x8 ah1 = *(const bf16x8*)(ap + 32);
    bf16x8 al0 = *(const bf16x8*)(aq);
    bf16x8 al1 = *(const bf16x8*)(aq + 32);
    f32x4 acc = {0.f, 0.f, 0.f, 0.f};
    acc = __builtin_amdgcn_mfma_f32_16x16x32_bf16(ah0, bh0, acc, 0, 0, 0);
    acc = __builtin_amdgcn_mfma_f32_16x16x32_bf16(ah1, bh1, acc, 0, 0, 0);
    acc = __builtin_amdgcn_mfma_f32_16x16x32_bf16(ah0, bl0, acc, 0, 0, 0);
    acc = __builtin_amdgcn_mfma_f32_16x16x32_bf16(ah1, bl1, acc, 0, 0, 0);
    acc = __builtin_amdgcn_mfma_f32_16x16x32_bf16(al0, bh0, acc, 0, 0, 0);
    acc = __builtin_amdgcn_mfma_f32_16x16x32_bf16(al1, bh1, acc, 0, 0, 0);
    int gn  = node0 + mt * 16 + quad * 4;
    int col = strip * 16 + r16;
#pragma unroll
    for (int r = 0; r < 4; r++) {
      if (gn + r < N_NODES)
        H2[(size_t)(gn + r) * 32 + col] = f2bf(acc[r] * dinv[gn + r]);
    }
  }
}

// ---------------- fused agg2 (FEAT=32) + decoder ----------------
// Block = 64 nodes: aggregate z rows (write Z global + LDS hi/lo), then the
// 2-stage decoder MFMA. h2 table must live OUTSIDE the recon region (race).

__global__ __launch_bounds__(256) void k_agg2_dec(
    const unsigned short* __restrict__ H2,
    const int* __restrict__ beg, const int* __restrict__ cnt,
    const int* __restrict__ csr4,
    const float* __restrict__ dinv, const float* __restrict__ bias,
    const unsigned short* __restrict__ D1hi, const unsigned short* __restrict__ D1lo,
    const float* __restrict__ bd1,
    const unsigned short* __restrict__ D2hi, const unsigned short* __restrict__ D2lo,
    const float* __restrict__ bd2,
    float* __restrict__ Z, float* __restrict__ RECON) {
  constexpr int KP1 = 40;   // 32+8
  constexpr int KP2 = 72;   // 64+8
  __shared__ __align__(16) unsigned short Azhi[64 * KP1];
  __shared__ __align__(16) unsigned short Azlo[64 * KP1];
  __shared__ __align__(16) unsigned short H3hi[64 * KP2];
  __shared__ __align__(16) unsigned short H3lo[64 * KP2];
  int t = threadIdx.x, w = t >> 6, lane = t & 63;
  int node0 = blockIdx.x * 64;
  int g = lane >> 2, f8 = lane & 3;    // 4 lanes/edge, 16 edges/gather

  for (int it = 0; it < 16; ++it) {
    int row  = it * 4 + w;
    int node = node0 + row;
    float a0=0.f,a1=0.f,a2=0.f,a3=0.f,a4=0.f,a5=0.f,a6=0.f,a7=0.f;
    if (node < N_NODES) {
      int bg = beg[node], end = bg + cnt[node];
      for (int p = bg; p < end; p += 64) {
        int   sarr[4]; float marr[4]; u16x8 harr[4];
#pragma unroll
        for (int b4 = 0; b4 < 4; b4++) {
          int q = p + b4 * 16 + g;
          sarr[b4] = (q < end) ? csr4[q] : node;
          marr[b4] = (q < end) ? 1.f : 0.f;
        }
#pragma unroll
        for (int b4 = 0; b4 < 4; b4++)
          harr[b4] = *(const u16x8*)(H2 + (size_t)sarr[b4] * 32 + f8 * 8);
#pragma unroll
        for (int b4 = 0; b4 < 4; b4++) {
          float m = marr[b4]; u16x8 h = harr[b4];
          a0 += bf2f(h[0]) * m; a1 += bf2f(h[1]) * m;
          a2 += bf2f(h[2]) * m; a3 += bf2f(h[3]) * m;
          a4 += bf2f(h[4]) * m; a5 += bf2f(h[5]) * m;
          a6 += bf2f(h[6]) * m; a7 += bf2f(h[7]) * m;
        }
      }
#pragma unroll
      for (int off = 4; off < 64; off <<= 1) {
        a0 += __shfl_xor(a0, off, 64); a1 += __shfl_xor(a1, off, 64);
        a2 += __shfl_xor(a2, off, 64); a3 += __shfl_xor(a3, off, 64);
        a4 += __shfl_xor(a4, off, 64); a5 += __shfl_xor(a5, off, 64);
        a6 += __shfl_xor(a6, off, 64); a7 += __shfl_xor(a7, off, 64);
      }
    }
    if (g == 0) {
      float vals[8] = {0.f,0.f,0.f,0.f,0.f,0.f,0.f,0.f};
      if (node < N_NODES) {
        float di = dinv[node];
        u16x8 hs = *(const u16x8*)(H2 + (size_t)node * 32 + f8 * 8);
        float4 bv0 = *(const float4*)(bias + f8 * 8);
        float4 bv1 = *(const float4*)(bias + f8 * 8 + 4);
        vals[0] = (a0 + bf2f(hs[0])) * di + bv0.x;
        vals[1] = (a1 + bf2f(hs[1])) * di + bv0.y;
        vals[2] = (a2 + bf2f(hs[2])) * di + bv0.z;
        vals[3] = (a3 + bf2f(hs[3])) * di + bv0.w;
        vals[4] = (a4 + bf2f(hs[4])) * di + bv1.x;
        vals[5] = (a5 + bf2f(hs[5])) * di + bv1.y;
        vals[6] = (a6 + bf2f(hs[6])) * di + bv1.z;
        vals[7] = (a7 + bf2f(hs[7])) * di + bv1.w;
        float4 o0; o0.x = vals[0]; o0.y = vals[1]; o0.z = vals[2]; o0.w = vals[3];
        float4 o1; o1.x = vals[4]; o1.y = vals[5]; o1.z = vals[6]; o1.w = vals[7];
        *(float4*)(Z + (size_t)node * 32 + f8 * 8)     = o0;
        *(float4*)(Z + (size_t)node * 32 + f8 * 8 + 4) = o1;
      }
      int base = row * KP1 + f8 * 8;
#pragma unroll
      for (int j = 0; j < 8; j++) {
        unsigned short h = f2bf(vals[j]);
        Azhi[base + j] = h;
        Azlo[base + j] = f2bf(vals[j] - bf2f(h));
      }
    }
  }
  __syncthreads();

  int quad = lane >> 4, r16 = lane & 15;

  {
    int col = w * 16 + r16;
    float bias1 = bd1[col];
    bf16x8 bh = *(const bf16x8*)(D1hi + col * KP1 + quad * 8);
    bf16x8 bl = *(const bf16x8*)(D1lo + col * KP1 + quad * 8);
#pragma unroll
    for (int m = 0; m < 4; m++) {
      bf16x8 ah = *(const bf16x8*)(Azhi + (m * 16 + r16) * KP1 + quad * 8);
      bf16x8 al = *(const bf16x8*)(Azlo + (m * 16 + r16) * KP1 + quad * 8);
      f32x4 acc = {0.f, 0.f, 0.f, 0.f};
      acc = __builtin_amdgcn_mfma_f32_16x16x32_bf16(ah, bh, acc, 0, 0, 0);
      acc = __builtin_amdgcn_mfma_f32_16x16x32_bf16(ah, bl, acc, 0, 0, 0);
      acc = __builtin_amdgcn_mfma_f32_16x16x32_bf16(al, bh, acc, 0, 0, 0);
#pragma unroll
      for (int r = 0; r < 4; r++) {
        int row = m * 16 + quad * 4 + r;
        float hv = fmaxf(acc[r] + bias1, 0.f);
        unsigned short h = f2bf(hv);
        H3hi[row * KP2 + col] = h;
        H3lo[row * KP2 + col] = f2bf(hv - bf2f(h));
      }
    }
  }
  __syncthreads();

#pragma unroll
  for (int sp = 0; sp < 2; sp++) {
    int strip = w + sp * 4;
    int col = strip * 16 + r16;
    float bias2 = bd2[col];
    const unsigned short* b2h = D2hi + col * KP2 + quad * 8;
    const unsigned short* b2l = D2lo + col * KP2 + quad * 8;
    bf16x8 bh0 = *(const bf16x8*)(b2h);
    bf16x8 bh1 = *(const bf16x8*)(b2h + 32);
    bf16x8 bl0 = *(const bf16x8*)(b2l);
    bf16x8 bl1 = *(const bf16x8*)(b2l + 32);
#pragma unroll
    for (int m = 0; m < 4; m++) {
      const unsigned short* ahp = H3hi + (m * 16 + r16) * KP2 + quad * 8;
      const unsigned short* alp = H3lo + (m * 16 + r16) * KP2 + quad * 8;
      bf16x8 ah0 = *(const bf16x8*)(ahp);
      bf16x8 ah1 = *(const bf16x8*)(ahp + 32);
      bf16x8 al0 = *(const bf16x8*)(alp);
      bf16x8 al1 = *(const bf16x8*)(alp + 32);
      f32x4 acc = {0.f, 0.f, 0.f, 0.f};
      acc = __builtin_amdgcn_mfma_f32_16x16x32_bf16(ah0, bh0, acc, 0, 0, 0);
      acc = __builtin_amdgcn_mfma_f32_16x16x32_bf16(ah1, bh1, acc, 0, 0, 0);
      acc = __builtin_amdgcn_mfma_f32_16x16x32_bf16(ah0, bl0, acc, 0, 0, 0);
      acc = __builtin_amdgcn_mfma_f32_16x16x32_bf16(ah1, bl1, acc, 0, 0, 0);
      acc = __builtin_amdgcn_mfma_f32_16x16x32_bf16(al0, bh0, acc, 0, 0, 0);
      acc = __builtin_amdgcn_mfma_f32_16x16x32_bf16(al1, bh1, acc, 0, 0, 0);
#pragma unroll
      for (int r = 0; r < 4; r++) {
        int n = node0 + m * 16 + quad * 4 + r;
        if (n < N_NODES) RECON[(size_t)n * 128 + col] = acc[r] + bias2;
      }
    }
  }
}

// ---------------- launch ----------------

extern "C" void kernel_launch(void* const* d_in, const int* in_sizes, int n_in,
                              void* d_out, int out_size, void* d_ws, size_t ws_size,
                              hipStream_t stream) {
  const float* x    = (const float*)d_in[0];
  const int*   eidx = (const int*)d_in[1];
  const int*   esrc = eidx;
  const int*   edst = eidx + N_EDGES;
  const float* W1  = (const float*)d_in[2];
  const float* b1  = (const float*)d_in[3];
  const float* W2  = (const float*)d_in[4];
  const float* b2  = (const float*)d_in[5];
  const float* Wd1 = (const float*)d_in[6];
  const float* bd1 = (const float*)d_in[7];
  const float* Wd2 = (const float*)d_in[8];
  const float* bd2 = (const float*)d_in[9];

  float* recon = (float*)d_out;                                  // [N,128]
  float* z     = (float*)d_out + (size_t)N_NODES * D_INF;        // [N,32]
  // recon region scratch: stage (7.2 MB) then h1_16 (12.8 MB). h2 lives in ws
  // because k_agg2_dec writes recon while other blocks still gather h2.
  int*            stage = (int*)recon;
  unsigned short* h1_16 = (unsigned short*)recon;

  char* ws = (char*)d_ws;
  int*   beg    = (int*)(ws + 0);              // 409,600
  int*   cntn   = (int*)(ws + 409600);         // 409,600
  float* dinv   = (float*)(ws + 819200);       // 409,600
  int*   bkcnt  = (int*)(ws + 1228800);        // 1,024
  int*   csr4   = (int*)(ws + 1229824);        // 7,225,344 (196*9216*4)
  unsigned short* w1hi  = (unsigned short*)(ws + 8455168);   // 17,408
  unsigned short* w1lo  = (unsigned short*)(ws + 8472576);   // 17,408
  unsigned short* w2hi  = (unsigned short*)(ws + 8489984);   //  4,608
  unsigned short* w2lo  = (unsigned short*)(ws + 8494592);   //  4,608
  unsigned short* wd1hi = (unsigned short*)(ws + 8499200);   //  5,120
  unsigned short* wd1lo = (unsigned short*)(ws + 8504320);   //  5,120
  unsigned short* wd2hi = (unsigned short*)(ws + 8509440);   // 18,432
  unsigned short* wd2lo = (unsigned short*)(ws + 8527872);   // 18,432
  unsigned short* h2_16 = (unsigned short*)(ws + 8546304);   // 6,400,000
  // total ws use: 14,946,304 B

  k_prep_w<<<5, 256, 0, stream>>>(W1, W2, Wd1, Wd2, w1hi, w1lo, w2hi, w2lo,
                                  wd1hi, wd1lo, wd2hi, wd2lo, bkcnt);
  k_binA<<<ABLOCKS, 256, 0, stream>>>(esrc, edst, bkcnt, stage);
  k_csr<<<NBKT, 1024, 0, stream>>>(stage, bkcnt, beg, cntn, dinv, csr4);

  // h1' = (x @ W1) * dinv  (bf16)  -- overwrites stage (dead after k_csr)
  k_mfma_gemm<64, 128, 64><<<(N_NODES + 63) / 64, 256, 0, stream>>>(x, w1hi, w1lo, dinv, h1_16);
  // z1 = relu(dinv*(sum h1' + self) + b1) [LDS only]; h2' = (z1 @ W2) * dinv
  k_agg1_gemm2<<<(N_NODES + 63) / 64, 256, 0, stream>>>(h1_16, beg, cntn, csr4, dinv, b1,
                                                        w2hi, w2lo, h2_16);
  // z = dinv*(sum h2' + self) + b2 (output); recon = relu(z@Wd1+bd1)@Wd2+bd2
  k_agg2_dec<<<(N_NODES + 63) / 64, 256, 0, stream>>>(h2_16, beg, cntn, csr4, dinv, b2,
                                                      wd1hi, wd1lo, bd1, wd2hi, wd2lo, bd2,
                                                      z, recon);
}

// Round 10
// 293.336 us; speedup vs baseline: 1.1134x; 1.1134x over previous
//
#include <hip/hip_runtime.h>
#include <stdint.h>

#define N_NODES 100000
#define N_EDGES 1600000
#define D_INF   128
#define D_HID   64
#define D_LAT   32

typedef __attribute__((ext_vector_type(8))) short bf16x8;
typedef __attribute__((ext_vector_type(4))) float f32x4;
typedef __attribute__((ext_vector_type(8))) unsigned short u16x8;

__device__ __forceinline__ unsigned short f2bf(float v) {
  union { float f; unsigned int u; } x; x.f = v;
  unsigned int u = x.u + 0x7FFF + ((x.u >> 16) & 1);   // RNE
  return (unsigned short)(u >> 16);
}
__device__ __forceinline__ float bf2f(unsigned short h) {
  union { unsigned int u; float f; } x; x.u = ((unsigned int)h) << 16;
  return x.f;
}

// ---------------- binned CSR build ----------------
// k_binA (EPB=2048): bins edges by dst>>9 into fixed-capacity bucket regions,
// PACKED as (src<<9)|dst_local. k_csr (1024 thr, one block per bucket):
// LDS histogram + scan + scatter.

#define NBKT      196    // ceil(100000 / 512)
#define BKT_SHIFT 9      // 512 nodes per bucket
#define BKT_CAP   10240  // fixed region capacity (mean 8192, sigma ~90)
#define EPB       2048   // edges per pass-A block
#define ABLOCKS   782    // ceil(1600000 / 2048)

__global__ __launch_bounds__(256) void k_binA(const int* __restrict__ esrc,
                                              const int* __restrict__ edst,
                                              int* __restrict__ bkcnt,
                                              int* __restrict__ stage) {
  __shared__ int cnt[NBKT];
  __shared__ int sc[256];
  __shared__ int garel[NBKT];
  __shared__ int pos[NBKT];
  __shared__ __align__(16) int2 stg[EPB];   // 16 KB
  int t = threadIdx.x;
  int e0 = blockIdx.x * EPB;

  for (int i = t; i < NBKT; i += 256) cnt[i] = 0;
  __syncthreads();

  int ds[8], ss[8];
  const int4* s4 = (const int4*)esrc;
  const int4* d4 = (const int4*)edst;
#pragma unroll
  for (int i = 0; i < 2; i++) {
    int idx4 = (e0 >> 2) + i * 256 + t;
    int4 dd = make_int4(-1, -1, -1, -1);
    int4 sv = make_int4(0, 0, 0, 0);
    if (idx4 < N_EDGES / 4) { dd = d4[idx4]; sv = s4[idx4]; }
    ds[i*4+0] = dd.x; ds[i*4+1] = dd.y; ds[i*4+2] = dd.z; ds[i*4+3] = dd.w;
    ss[i*4+0] = sv.x; ss[i*4+1] = sv.y; ss[i*4+2] = sv.z; ss[i*4+3] = sv.w;
  }
#pragma unroll
  for (int j = 0; j < 8; j++)
    if (ds[j] >= 0) atomicAdd(&cnt[ds[j] >> BKT_SHIFT], 1);
  __syncthreads();

  int c = (t < NBKT) ? cnt[t] : 0;
  sc[t] = c;
  __syncthreads();
  int incl = c;
#pragma unroll
  for (int off = 1; off < 256; off <<= 1) {
    int x = (t >= off) ? sc[t - off] : 0;
    __syncthreads();
    incl += x;
    sc[t] = incl;
    __syncthreads();
  }
  if (t < NBKT) {
    int lb = incl - c;
    int gb = 0;
    if (c > 0) gb = t * BKT_CAP + atomicAdd(&bkcnt[t], c);
    garel[t] = gb - lb;
    pos[t]   = lb;
  }
  __syncthreads();

#pragma unroll
  for (int j = 0; j < 8; j++) {
    if (ds[j] >= 0) {
      int b  = ds[j] >> BKT_SHIFT;
      int lp = atomicAdd(&pos[b], 1);
      stg[lp] = make_int2(ss[j], ds[j]);
    }
  }
  __syncthreads();

  int nval = N_EDGES - e0; if (nval > EPB) nval = EPB;
  for (int i = t; i < nval; i += 256) {
    int2 e = stg[i];
    stage[garel[e.y >> BKT_SHIFT] + i] = (e.x << BKT_SHIFT) | (e.y & 511);
  }
}

// one block per bucket: histogram + scan + scatter, all bucket-local
__global__ __launch_bounds__(1024) void k_csr(const int* __restrict__ stage,
                                              const int* __restrict__ bkcnt,
                                              int* __restrict__ beg,
                                              int* __restrict__ cnt,
                                              float* __restrict__ dinv,
                                              int* __restrict__ csr4) {
  __shared__ int hist[512];
  __shared__ int scan[512];
  int b = blockIdx.x, t = threadIdx.x;
  if (t < 512) hist[t] = 0;
  __syncthreads();
  int n = bkcnt[b];
  int nlo = b << BKT_SHIFT;
  const int* reg = stage + (size_t)b * BKT_CAP;
  for (int i = t; i < n; i += 1024)
    atomicAdd(&hist[reg[i] & 511], 1);
  __syncthreads();
  int v = (t < 512) ? hist[t] : 0;
  if (t < 512) scan[t] = v;
  __syncthreads();
  int incl = v;
#pragma unroll
  for (int off = 1; off < 512; off <<= 1) {
    int x = (t >= off && t < 512) ? scan[t - off] : 0;
    __syncthreads();
    if (t < 512) { incl += x; scan[t] = incl; }
    __syncthreads();
  }
  if (t < 512) {
    int loc = incl - v;
    int node = nlo + t;
    if (node < N_NODES) {
      beg[node]  = b * BKT_CAP + loc;
      cnt[node]  = v;
      dinv[node] = rsqrtf((float)(v + 1));
    }
    scan[t] = loc;
  }
  __syncthreads();
  int* c4 = csr4 + (size_t)b * BKT_CAP;
  for (int i = t; i < n; i += 1024) {
    int e = reg[i];
    int slot = atomicAdd(&scan[e & 511], 1);
    c4[slot] = e >> BKT_SHIFT;
  }
}

// ---------------- weight prep (block 4 zeroes bkcnt) ----------------

__global__ void k_prep_w(const float* __restrict__ W1, const float* __restrict__ W2,
                         const float* __restrict__ Wd1, const float* __restrict__ Wd2,
                         unsigned short* __restrict__ w1hi, unsigned short* __restrict__ w1lo,
                         unsigned short* __restrict__ w2hi, unsigned short* __restrict__ w2lo,
                         unsigned short* __restrict__ wd1hi, unsigned short* __restrict__ wd1lo,
                         unsigned short* __restrict__ wd2hi, unsigned short* __restrict__ wd2lo,
                         int* __restrict__ bkcnt) {
  if (blockIdx.x == 4) {
    if (threadIdx.x < NBKT) bkcnt[threadIdx.x] = 0;
    return;
  }
  const float* src; unsigned short *hi, *lo; int K, M;
  switch (blockIdx.x) {
    case 0:  src = W1;  hi = w1hi;  lo = w1lo;  K = 128; M = 64;  break;
    case 1:  src = W2;  hi = w2hi;  lo = w2lo;  K = 64;  M = 32;  break;
    case 2:  src = Wd1; hi = wd1hi; lo = wd1lo; K = 32;  M = 64;  break;
    default: src = Wd2; hi = wd2hi; lo = wd2lo; K = 64;  M = 128; break;
  }
  int KP = K + 8;
  for (int i = threadIdx.x; i < K * M; i += 256) {
    int k = i / M, c = i % M;
    float v = src[i];
    unsigned short h = f2bf(v);
    hi[c * KP + k] = h;
    lo[c * KP + k] = f2bf(v - bf2f(h));
  }
}

// ---------------- MFMA GEMM: Y[N,M] = (X[N,K] @ W[K,M]) * dinv[n], bf16 out --------

template<int NODES, int K, int M>
__global__ __launch_bounds__(256) void k_mfma_gemm(const float* __restrict__ X,
                                                   const unsigned short* __restrict__ Bhi,
                                                   const unsigned short* __restrict__ Blo,
                                                   const float* __restrict__ dinv,
                                                   unsigned short* __restrict__ Y16) {
  constexpr int KP     = K + 8;
  constexpr int NSTRIP = M / 16;
  constexpr int KSTEPS = K / 32;
  constexpr int MTW    = (NODES / 16) * NSTRIP / 4;
  __shared__ __align__(16) unsigned short Ahi[NODES * KP];
  __shared__ __align__(16) unsigned short Alo[NODES * KP];

  int t = threadIdx.x;
  int node0 = blockIdx.x * NODES;

  for (int i = t; i < NODES * K / 4; i += 256) {
    int n = i / (K / 4), f4 = i % (K / 4);
    float4 v = make_float4(0.f, 0.f, 0.f, 0.f);
    if (node0 + n < N_NODES) v = ((const float4*)(X + (size_t)(node0 + n) * K))[f4];
    int base = n * KP + f4 * 4;
    float vv[4] = {v.x, v.y, v.z, v.w};
#pragma unroll
    for (int j = 0; j < 4; j++) {
      unsigned short h = f2bf(vv[j]);
      Ahi[base + j] = h;
      Alo[base + j] = f2bf(vv[j] - bf2f(h));
    }
  }
  __syncthreads();

  int w = t >> 6, lane = t & 63;
  int quad = lane >> 4, r16 = lane & 15;
  int strip = w % NSTRIP;

  bf16x8 bh[KSTEPS], bl[KSTEPS];
  const unsigned short* bp = Bhi + (strip * 16 + r16) * KP + quad * 8;
  const unsigned short* bq = Blo + (strip * 16 + r16) * KP + quad * 8;
#pragma unroll
  for (int ks = 0; ks < KSTEPS; ks++) {
    bh[ks] = *(const bf16x8*)(bp + ks * 32);
    bl[ks] = *(const bf16x8*)(bq + ks * 32);
  }

#pragma unroll
  for (int c = 0; c < MTW; c++) {
    int mt = (w / NSTRIP) * MTW + c;
    f32x4 acc = {0.f, 0.f, 0.f, 0.f};
    const unsigned short* ap = &Ahi[(mt * 16 + r16) * KP + quad * 8];
    const unsigned short* aq = &Alo[(mt * 16 + r16) * KP + quad * 8];
#pragma unroll
    for (int ks = 0; ks < KSTEPS; ks++) {
      bf16x8 ah = *(const bf16x8*)(ap + ks * 32);
      bf16x8 al = *(const bf16x8*)(aq + ks * 32);
      acc = __builtin_amdgcn_mfma_f32_16x16x32_bf16(ah, bh[ks], acc, 0, 0, 0);
      acc = __builtin_amdgcn_mfma_f32_16x16x32_bf16(ah, bl[ks], acc, 0, 0, 0);
      acc = __builtin_amdgcn_mfma_f32_16x16x32_bf16(al, bh[ks], acc, 0, 0, 0);
    }
    int gn  = node0 + mt * 16 + quad * 4;
    int col = strip * 16 + r16;
#pragma unroll
    for (int r = 0; r < 4; r++) {
      if (gn + r < N_NODES)
        Y16[(size_t)(gn + r) * M + col] = f2bf(acc[r] * dinv[gn + r]);
    }
  }
}

// ---------------- aggregation (round 13: preloaded-index gathers) ----------
// One coalesced 64-lane csr4 load per 64-edge chunk; indices distributed via
// __shfl (ds_bpermute), so row gathers have NO dependent index load in the
// chain. Second half of chunk branch-skipped when deg <= 32 (99.98% of nodes).

template<int FEAT, bool RELU>
__global__ __launch_bounds__(256) void k_aggregate(const unsigned short* __restrict__ H16,
                            const int* __restrict__ beg,
                            const int* __restrict__ cnt,
                            const int* __restrict__ csr4,
                            const float* __restrict__ dinv, const float* __restrict__ bias,
                            float* __restrict__ OUT) {
  constexpr int LPE    = FEAT / 8;   // lanes per edge (8 or 4)
  constexpr int GROUPS = 64 / LPE;   // edges per wave gather (8 or 16)
  constexpr int BH     = 32 / GROUPS; // batches per half-chunk (4 or 2)

  int node = blockIdx.x * 4 + (threadIdx.x >> 6);
  int lane = threadIdx.x & 63;
  if (node >= N_NODES) return;
  int bg = beg[node], end = bg + cnt[node];
  int g  = lane / LPE;               // which edge of the batch
  int f8 = lane % LPE;               // which feature octet

  float a0=0.f,a1=0.f,a2=0.f,a3=0.f,a4=0.f,a5=0.f,a6=0.f,a7=0.f;

  for (int p = bg; p < end; p += 64) {
    int q64 = p + lane;
    int idx = csr4[(q64 < end) ? q64 : (end - 1)];   // one coalesced load / chunk
#pragma unroll
    for (int half = 0; half < 2; half++) {
      if (half == 1 && p + 32 >= end) break;
      int   sarr[BH]; float marr[BH]; u16x8 harr[BH];
#pragma unroll
      for (int b = 0; b < BH; b++) {
        int e = (half * BH + b) * GROUPS + g;
        int s = __shfl(idx, e, 64);
        bool v = (p + e < end);
        sarr[b] = v ? s : node;
        marr[b] = v ? 1.f : 0.f;
      }
#pragma unroll
      for (int b = 0; b < BH; b++)
        harr[b] = *(const u16x8*)(H16 + (size_t)sarr[b] * FEAT + f8 * 8);
#pragma unroll
      for (int b = 0; b < BH; b++) {
        float m = marr[b]; u16x8 h = harr[b];
        a0 += bf2f(h[0]) * m; a1 += bf2f(h[1]) * m;
        a2 += bf2f(h[2]) * m; a3 += bf2f(h[3]) * m;
        a4 += bf2f(h[4]) * m; a5 += bf2f(h[5]) * m;
        a6 += bf2f(h[6]) * m; a7 += bf2f(h[7]) * m;
      }
    }
  }

  // fold edge-groups together (g lives in the upper lane bits)
#pragma unroll
  for (int off = LPE; off < 64; off <<= 1) {
    a0 += __shfl_xor(a0, off, 64);
    a1 += __shfl_xor(a1, off, 64);
    a2 += __shfl_xor(a2, off, 64);
    a3 += __shfl_xor(a3, off, 64);
    a4 += __shfl_xor(a4, off, 64);
    a5 += __shfl_xor(a5, off, 64);
    a6 += __shfl_xor(a6, off, 64);
    a7 += __shfl_xor(a7, off, 64);
  }

  if (g == 0) {
    float di = dinv[node];
    u16x8 hs = *(const u16x8*)(H16 + (size_t)node * FEAT + f8 * 8);
    float4 bv0 = *(const float4*)(bias + f8 * 8);
    float4 bv1 = *(const float4*)(bias + f8 * 8 + 4);
    a0 = (a0 + bf2f(hs[0])) * di + bv0.x;
    a1 = (a1 + bf2f(hs[1])) * di + bv0.y;
    a2 = (a2 + bf2f(hs[2])) * di + bv0.z;
    a3 = (a3 + bf2f(hs[3])) * di + bv0.w;
    a4 = (a4 + bf2f(hs[4])) * di + bv1.x;
    a5 = (a5 + bf2f(hs[5])) * di + bv1.y;
    a6 = (a6 + bf2f(hs[6])) * di + bv1.z;
    a7 = (a7 + bf2f(hs[7])) * di + bv1.w;
    if (RELU) {
      a0 = fmaxf(a0, 0.f); a1 = fmaxf(a1, 0.f);
      a2 = fmaxf(a2, 0.f); a3 = fmaxf(a3, 0.f);
      a4 = fmaxf(a4, 0.f); a5 = fmaxf(a5, 0.f);
      a6 = fmaxf(a6, 0.f); a7 = fmaxf(a7, 0.f);
    }
    float4 o0; o0.x = a0; o0.y = a1; o0.z = a2; o0.w = a3;
    float4 o1; o1.x = a4; o1.y = a5; o1.z = a6; o1.w = a7;
    *(float4*)(OUT + (size_t)node * FEAT + f8 * 8)     = o0;
    *(float4*)(OUT + (size_t)node * FEAT + f8 * 8 + 4) = o1;
  }
}

// ---------------- decoder: fused 2-stage MFMA ----------------

__global__ __launch_bounds__(256) void k_decoder_mfma(
    const float* __restrict__ Z,
    const unsigned short* __restrict__ B1hi, const unsigned short* __restrict__ B1lo,
    const float* __restrict__ bd1,
    const unsigned short* __restrict__ B2hi, const unsigned short* __restrict__ B2lo,
    const float* __restrict__ bd2, float* __restrict__ RECON) {
  constexpr int KP1 = 40;   // 32+8
  constexpr int KP2 = 72;   // 64+8
  __shared__ __align__(16) unsigned short Azhi[64 * KP1];
  __shared__ __align__(16) unsigned short Azlo[64 * KP1];
  __shared__ __align__(16) unsigned short H3hi[64 * KP2];
  __shared__ __align__(16) unsigned short H3lo[64 * KP2];
  int t = threadIdx.x;
  int node0 = blockIdx.x * 64;

  for (int i = t; i < 512; i += 256) {
    int n = i >> 3, f4 = i & 7;
    float4 v = make_float4(0.f, 0.f, 0.f, 0.f);
    if (node0 + n < N_NODES) v = ((const float4*)(Z + (size_t)(node0 + n) * 32))[f4];
    int base = n * KP1 + f4 * 4;
    float vv[4] = {v.x, v.y, v.z, v.w};
#pragma unroll
    for (int j = 0; j < 4; j++) {
      unsigned short h = f2bf(vv[j]);
      Azhi[base + j] = h;
      Azlo[base + j] = f2bf(vv[j] - bf2f(h));
    }
  }
  __syncthreads();

  int w = t >> 6, lane = t & 63;
  int quad = lane >> 4, r16 = lane & 15;

  {
    int col = w * 16 + r16;
    float bias1 = bd1[col];
    bf16x8 bh = *(const bf16x8*)(B1hi + col * KP1 + quad * 8);
    bf16x8 bl = *(const bf16x8*)(B1lo + col * KP1 + quad * 8);
#pragma unroll
    for (int m = 0; m < 4; m++) {
      bf16x8 ah = *(const bf16x8*)(Azhi + (m * 16 + r16) * KP1 + quad * 8);
      bf16x8 al = *(const bf16x8*)(Azlo + (m * 16 + r16) * KP1 + quad * 8);
      f32x4 acc = {0.f, 0.f, 0.f, 0.f};
      acc = __builtin_amdgcn_mfma_f32_16x16x32_bf16(ah, bh, acc, 0, 0, 0);
      acc = __builtin_amdgcn_mfma_f32_16x16x32_bf16(ah, bl, acc, 0, 0, 0);
      acc = __builtin_amdgcn_mfma_f32_16x16x32_bf16(al, bh, acc, 0, 0, 0);
#pragma unroll
      for (int r = 0; r < 4; r++) {
        int row = m * 16 + quad * 4 + r;
        float hv = fmaxf(acc[r] + bias1, 0.f);
        unsigned short h = f2bf(hv);
        H3hi[row * KP2 + col] = h;
        H3lo[row * KP2 + col] = f2bf(hv - bf2f(h));
      }
    }
  }
  __syncthreads();

#pragma unroll
  for (int sp = 0; sp < 2; sp++) {
    int strip = w + sp * 4;
    int col = strip * 16 + r16;
    float bias2 = bd2[col];
    const unsigned short* b2h = B2hi + col * KP2 + quad * 8;
    const unsigned short* b2l = B2lo + col * KP2 + quad * 8;
    bf16x8 bh0 = *(const bf16x8*)(b2h);
    bf16x8 bh1 = *(const bf16x8*)(b2h + 32);
    bf16x8 bl0 = *(const bf16x8*)(b2l);
    bf16x8 bl1 = *(const bf16x8*)(b2l + 32);
#pragma unroll
    for (int m = 0; m < 4; m++) {
      const unsigned short* ahp = H3hi + (m * 16 + r16) * KP2 + quad * 8;
      const unsigned short* alp = H3lo + (m * 16 + r16) * KP2 + quad * 8;
      bf16x8 ah0 = *(const bf16x8*)(ahp);
      bf16x8 ah1 = *(const bf16x8*)(ahp + 32);
      bf16x8 al0 = *(const bf16x8*)(alp);
      bf16x8 al1 = *(const bf16x8*)(alp + 32);
      f32x4 acc = {0.f, 0.f, 0.f, 0.f};
      acc = __builtin_amdgcn_mfma_f32_16x16x32_bf16(ah0, bh0, acc, 0, 0, 0);
      acc = __builtin_amdgcn_mfma_f32_16x16x32_bf16(ah1, bh1, acc, 0, 0, 0);
      acc = __builtin_amdgcn_mfma_f32_16x16x32_bf16(ah0, bl0, acc, 0, 0, 0);
      acc = __builtin_amdgcn_mfma_f32_16x16x32_bf16(ah1, bl1, acc, 0, 0, 0);
      acc = __builtin_amdgcn_mfma_f32_16x16x32_bf16(al0, bh0, acc, 0, 0, 0);
      acc = __builtin_amdgcn_mfma_f32_16x16x32_bf16(al1, bh1, acc, 0, 0, 0);
#pragma unroll
      for (int r = 0; r < 4; r++) {
        int n = node0 + m * 16 + quad * 4 + r;
        if (n < N_NODES) RECON[(size_t)n * 128 + col] = acc[r] + bias2;
      }
    }
  }
}

// ---------------- launch ----------------

extern "C" void kernel_launch(void* const* d_in, const int* in_sizes, int n_in,
                              void* d_out, int out_size, void* d_ws, size_t ws_size,
                              hipStream_t stream) {
  const float* x    = (const float*)d_in[0];
  const int*   eidx = (const int*)d_in[1];
  const int*   esrc = eidx;
  const int*   edst = eidx + N_EDGES;
  const float* W1  = (const float*)d_in[2];
  const float* b1  = (const float*)d_in[3];
  const float* W2  = (const float*)d_in[4];
  const float* b2  = (const float*)d_in[5];
  const float* Wd1 = (const float*)d_in[6];
  const float* bd1 = (const float*)d_in[7];
  const float* Wd2 = (const float*)d_in[8];
  const float* bd2 = (const float*)d_in[9];

  float* recon = (float*)d_out;                                  // [N,128]
  float* z     = (float*)d_out + (size_t)N_NODES * D_INF;        // [N,32]
  // Scratch in the dead recon region (51.2 MB, written only by k_decoder_mfma):
  //   stage [196*10240] int @ +0     (8.03 MB)  -- packed binned edges; dead
  //                                               after k_csr, region reused:
  //   h1_16 [N,64] bf16 @ +0         (12.8 MB)
  //   z1    [N,64] fp32 @ +12.8 MB   (25.6 MB)
  //   h2_16 [N,32] bf16 @ +38.4 MB   ( 6.4 MB)   -> total 44.8 MB < 51.2 MB
  int*            stage = (int*)recon;
  unsigned short* h1_16 = (unsigned short*)recon;
  float*          z1    = (float*)((char*)recon + 12800000);
  unsigned short* h2_16 = (unsigned short*)((char*)recon + 38400000);

  char* ws = (char*)d_ws;
  int*   beg    = (int*)(ws + 0);              // 409,600
  int*   cntn   = (int*)(ws + 409600);         // 409,600
  float* dinv   = (float*)(ws + 819200);       // 409,600
  int*   bkcnt  = (int*)(ws + 1228800);        // 1,024
  int*   csr4   = (int*)(ws + 1229824);        // 8,028,160 (196*10240*4)
  unsigned short* w1hi  = (unsigned short*)(ws + 9257984);   // 17,408
  unsigned short* w1lo  = (unsigned short*)(ws + 9275392);   // 17,408
  unsigned short* w2hi  = (unsigned short*)(ws + 9292800);   //  4,608
  unsigned short* w2lo  = (unsigned short*)(ws + 9297408);   //  4,608
  unsigned short* wd1hi = (unsigned short*)(ws + 9302016);   //  5,120
  unsigned short* wd1lo = (unsigned short*)(ws + 9307136);   //  5,120
  unsigned short* wd2hi = (unsigned short*)(ws + 9312256);   // 18,432
  unsigned short* wd2lo = (unsigned short*)(ws + 9330688);   // 18,432
  // total ws use: 9,349,120 B

  k_prep_w<<<5, 256, 0, stream>>>(W1, W2, Wd1, Wd2, w1hi, w1lo, w2hi, w2lo,
                                  wd1hi, wd1lo, wd2hi, wd2lo, bkcnt);
  k_binA<<<ABLOCKS, 256, 0, stream>>>(esrc, edst, bkcnt, stage);
  k_csr<<<NBKT, 1024, 0, stream>>>(stage, bkcnt, beg, cntn, dinv, csr4);

  // h1' = (x @ W1) * dinv  (bf16)  -- overwrites stage (dead after k_csr)
  k_mfma_gemm<64, 128, 64><<<(N_NODES + 63) / 64, 256, 0, stream>>>(x, w1hi, w1lo, dinv, h1_16);
  // z1 = relu(dinv*(sum h1' + self) + b1)  (fp32 out)
  k_aggregate<64, true><<<(N_NODES + 3) / 4, 256, 0, stream>>>(h1_16, beg, cntn, csr4, dinv, b1, z1);
  // h2' = (z1 @ W2) * dinv  (bf16 out)
  k_mfma_gemm<64, 64, 32><<<(N_NODES + 63) / 64, 256, 0, stream>>>(z1, w2hi, w2lo, dinv, h2_16);
  // z = dinv*(sum h2' + self) + b2  (latent output, fp32)
  k_aggregate<32, false><<<(N_NODES + 3) / 4, 256, 0, stream>>>(h2_16, beg, cntn, csr4, dinv, b2, z);
  // recon = relu(z@Wd1+bd1) @ Wd2 + bd2
  k_decoder_mfma<<<(N_NODES + 63) / 64, 256, 0, stream>>>(z, wd1hi, wd1lo, bd1,
                                                          wd2hi, wd2lo, bd2, recon);
}

// Round 11
// 292.889 us; speedup vs baseline: 1.1151x; 1.0015x over previous
//
#include <hip/hip_runtime.h>
#include <stdint.h>

#define N_NODES 100000
#define N_EDGES 1600000
#define D_INF   128
#define D_HID   64
#define D_LAT   32

typedef __attribute__((ext_vector_type(8))) short bf16x8;
typedef __attribute__((ext_vector_type(4))) float f32x4;
typedef __attribute__((ext_vector_type(8))) unsigned short u16x8;

__device__ __forceinline__ unsigned short f2bf(float v) {
  union { float f; unsigned int u; } x; x.f = v;
  unsigned int u = x.u + 0x7FFF + ((x.u >> 16) & 1);   // RNE
  return (unsigned short)(u >> 16);
}
__device__ __forceinline__ float bf2f(unsigned short h) {
  union { unsigned int u; float f; } x; x.u = ((unsigned int)h) << 16;
  return x.f;
}

// ---------------- binned CSR build ----------------
// k_binA (EPB=2048): bins edges by dst>>9 into fixed-capacity bucket regions,
// PACKED as (src<<9)|dst_local. k_csr (1024 thr, one block per bucket):
// LDS histogram + scan + scatter.

#define NBKT      196    // ceil(100000 / 512)
#define BKT_SHIFT 9      // 512 nodes per bucket
#define BKT_CAP   10240  // fixed region capacity (mean 8192, sigma ~90)
#define EPB       2048   // edges per pass-A block
#define ABLOCKS   782    // ceil(1600000 / 2048)

__global__ __launch_bounds__(256) void k_binA(const int* __restrict__ esrc,
                                              const int* __restrict__ edst,
                                              int* __restrict__ bkcnt,
                                              int* __restrict__ stage) {
  __shared__ int cnt[NBKT];
  __shared__ int sc[256];
  __shared__ int garel[NBKT];
  __shared__ int pos[NBKT];
  __shared__ __align__(16) int2 stg[EPB];   // 16 KB
  int t = threadIdx.x;
  int e0 = blockIdx.x * EPB;

  for (int i = t; i < NBKT; i += 256) cnt[i] = 0;
  __syncthreads();

  int ds[8], ss[8];
  const int4* s4 = (const int4*)esrc;
  const int4* d4 = (const int4*)edst;
#pragma unroll
  for (int i = 0; i < 2; i++) {
    int idx4 = (e0 >> 2) + i * 256 + t;
    int4 dd = make_int4(-1, -1, -1, -1);
    int4 sv = make_int4(0, 0, 0, 0);
    if (idx4 < N_EDGES / 4) { dd = d4[idx4]; sv = s4[idx4]; }
    ds[i*4+0] = dd.x; ds[i*4+1] = dd.y; ds[i*4+2] = dd.z; ds[i*4+3] = dd.w;
    ss[i*4+0] = sv.x; ss[i*4+1] = sv.y; ss[i*4+2] = sv.z; ss[i*4+3] = sv.w;
  }
#pragma unroll
  for (int j = 0; j < 8; j++)
    if (ds[j] >= 0) atomicAdd(&cnt[ds[j] >> BKT_SHIFT], 1);
  __syncthreads();

  int c = (t < NBKT) ? cnt[t] : 0;
  sc[t] = c;
  __syncthreads();
  int incl = c;
#pragma unroll
  for (int off = 1; off < 256; off <<= 1) {
    int x = (t >= off) ? sc[t - off] : 0;
    __syncthreads();
    incl += x;
    sc[t] = incl;
    __syncthreads();
  }
  if (t < NBKT) {
    int lb = incl - c;
    int gb = 0;
    if (c > 0) gb = t * BKT_CAP + atomicAdd(&bkcnt[t], c);
    garel[t] = gb - lb;
    pos[t]   = lb;
  }
  __syncthreads();

#pragma unroll
  for (int j = 0; j < 8; j++) {
    if (ds[j] >= 0) {
      int b  = ds[j] >> BKT_SHIFT;
      int lp = atomicAdd(&pos[b], 1);
      stg[lp] = make_int2(ss[j], ds[j]);
    }
  }
  __syncthreads();

  int nval = N_EDGES - e0; if (nval > EPB) nval = EPB;
  for (int i = t; i < nval; i += 256) {
    int2 e = stg[i];
    stage[garel[e.y >> BKT_SHIFT] + i] = (e.x << BKT_SHIFT) | (e.y & 511);
  }
}

// one block per bucket: histogram + scan + scatter, all bucket-local
__global__ __launch_bounds__(1024) void k_csr(const int* __restrict__ stage,
                                              const int* __restrict__ bkcnt,
                                              int* __restrict__ beg,
                                              int* __restrict__ cnt,
                                              float* __restrict__ dinv,
                                              int* __restrict__ csr4) {
  __shared__ int hist[512];
  __shared__ int scan[512];
  int b = blockIdx.x, t = threadIdx.x;
  if (t < 512) hist[t] = 0;
  __syncthreads();
  int n = bkcnt[b];
  int nlo = b << BKT_SHIFT;
  const int* reg = stage + (size_t)b * BKT_CAP;
  for (int i = t; i < n; i += 1024)
    atomicAdd(&hist[reg[i] & 511], 1);
  __syncthreads();
  int v = (t < 512) ? hist[t] : 0;
  if (t < 512) scan[t] = v;
  __syncthreads();
  int incl = v;
#pragma unroll
  for (int off = 1; off < 512; off <<= 1) {
    int x = (t >= off && t < 512) ? scan[t - off] : 0;
    __syncthreads();
    if (t < 512) { incl += x; scan[t] = incl; }
    __syncthreads();
  }
  if (t < 512) {
    int loc = incl - v;
    int node = nlo + t;
    if (node < N_NODES) {
      beg[node]  = b * BKT_CAP + loc;
      cnt[node]  = v;
      dinv[node] = rsqrtf((float)(v + 1));
    }
    scan[t] = loc;
  }
  __syncthreads();
  int* c4 = csr4 + (size_t)b * BKT_CAP;
  for (int i = t; i < n; i += 1024) {
    int e = reg[i];
    int slot = atomicAdd(&scan[e & 511], 1);
    c4[slot] = e >> BKT_SHIFT;
  }
}

// ---------------- weight prep (block 4 zeroes bkcnt) ----------------

__global__ void k_prep_w(const float* __restrict__ W1, const float* __restrict__ W2,
                         const float* __restrict__ Wd1, const float* __restrict__ Wd2,
                         unsigned short* __restrict__ w1hi, unsigned short* __restrict__ w1lo,
                         unsigned short* __restrict__ w2hi, unsigned short* __restrict__ w2lo,
                         unsigned short* __restrict__ wd1hi, unsigned short* __restrict__ wd1lo,
                         unsigned short* __restrict__ wd2hi, unsigned short* __restrict__ wd2lo,
                         int* __restrict__ bkcnt) {
  if (blockIdx.x == 4) {
    if (threadIdx.x < NBKT) bkcnt[threadIdx.x] = 0;
    return;
  }
  const float* src; unsigned short *hi, *lo; int K, M;
  switch (blockIdx.x) {
    case 0:  src = W1;  hi = w1hi;  lo = w1lo;  K = 128; M = 64;  break;
    case 1:  src = W2;  hi = w2hi;  lo = w2lo;  K = 64;  M = 32;  break;
    case 2:  src = Wd1; hi = wd1hi; lo = wd1lo; K = 32;  M = 64;  break;
    default: src = Wd2; hi = wd2hi; lo = wd2lo; K = 64;  M = 128; break;
  }
  int KP = K + 8;
  for (int i = threadIdx.x; i < K * M; i += 256) {
    int k = i / M, c = i % M;
    float v = src[i];
    unsigned short h = f2bf(v);
    hi[c * KP + k] = h;
    lo[c * KP + k] = f2bf(v - bf2f(h));
  }
}

// ---------------- MFMA GEMM: Y[N,M] = (X[N,K] @ W[K,M]) * dinv[n], bf16 out --------
// Row N_NODES of Y16 is written as an all-zero row (gather target for masked
// lanes in the aggregate -> no mask arithmetic in the hot loop).

template<int NODES, int K, int M>
__global__ __launch_bounds__(256) void k_mfma_gemm(const float* __restrict__ X,
                                                   const unsigned short* __restrict__ Bhi,
                                                   const unsigned short* __restrict__ Blo,
                                                   const float* __restrict__ dinv,
                                                   unsigned short* __restrict__ Y16) {
  constexpr int KP     = K + 8;
  constexpr int NSTRIP = M / 16;
  constexpr int KSTEPS = K / 32;
  constexpr int MTW    = (NODES / 16) * NSTRIP / 4;
  __shared__ __align__(16) unsigned short Ahi[NODES * KP];
  __shared__ __align__(16) unsigned short Alo[NODES * KP];

  int t = threadIdx.x;
  int node0 = blockIdx.x * NODES;

  for (int i = t; i < NODES * K / 4; i += 256) {
    int n = i / (K / 4), f4 = i % (K / 4);
    float4 v = make_float4(0.f, 0.f, 0.f, 0.f);
    if (node0 + n < N_NODES) v = ((const float4*)(X + (size_t)(node0 + n) * K))[f4];
    int base = n * KP + f4 * 4;
    float vv[4] = {v.x, v.y, v.z, v.w};
#pragma unroll
    for (int j = 0; j < 4; j++) {
      unsigned short h = f2bf(vv[j]);
      Ahi[base + j] = h;
      Alo[base + j] = f2bf(vv[j] - bf2f(h));
    }
  }
  __syncthreads();

  int w = t >> 6, lane = t & 63;
  int quad = lane >> 4, r16 = lane & 15;
  int strip = w % NSTRIP;

  bf16x8 bh[KSTEPS], bl[KSTEPS];
  const unsigned short* bp = Bhi + (strip * 16 + r16) * KP + quad * 8;
  const unsigned short* bq = Blo + (strip * 16 + r16) * KP + quad * 8;
#pragma unroll
  for (int ks = 0; ks < KSTEPS; ks++) {
    bh[ks] = *(const bf16x8*)(bp + ks * 32);
    bl[ks] = *(const bf16x8*)(bq + ks * 32);
  }

#pragma unroll
  for (int c = 0; c < MTW; c++) {
    int mt = (w / NSTRIP) * MTW + c;
    f32x4 acc = {0.f, 0.f, 0.f, 0.f};
    const unsigned short* ap = &Ahi[(mt * 16 + r16) * KP + quad * 8];
    const unsigned short* aq = &Alo[(mt * 16 + r16) * KP + quad * 8];
#pragma unroll
    for (int ks = 0; ks < KSTEPS; ks++) {
      bf16x8 ah = *(const bf16x8*)(ap + ks * 32);
      bf16x8 al = *(const bf16x8*)(aq + ks * 32);
      acc = __builtin_amdgcn_mfma_f32_16x16x32_bf16(ah, bh[ks], acc, 0, 0, 0);
      acc = __builtin_amdgcn_mfma_f32_16x16x32_bf16(ah, bl[ks], acc, 0, 0, 0);
      acc = __builtin_amdgcn_mfma_f32_16x16x32_bf16(al, bh[ks], acc, 0, 0, 0);
    }
    int gn  = node0 + mt * 16 + quad * 4;
    int col = strip * 16 + r16;
#pragma unroll
    for (int r = 0; r < 4; r++) {
      int n = gn + r;
      if (n <= N_NODES)
        Y16[(size_t)n * M + col] = f2bf(n < N_NODES ? acc[r] * dinv[n] : 0.f);
    }
  }
}

// ---------------- aggregation (round 14: zero-row, maskless inner loop) --------
// One coalesced 64-lane csr4 load per 64-edge chunk, indices via __shfl.
// Masked lanes gather the all-zero row at index N_NODES (wave-uniform ->
// L1 broadcast) so the accumulate is an unmasked add.

template<int FEAT, bool RELU>
__global__ __launch_bounds__(256) void k_aggregate(const unsigned short* __restrict__ H16,
                            const int* __restrict__ beg,
                            const int* __restrict__ cnt,
                            const int* __restrict__ csr4,
                            const float* __restrict__ dinv, const float* __restrict__ bias,
                            float* __restrict__ OUT) {
  constexpr int LPE    = FEAT / 8;   // lanes per edge (8 or 4)
  constexpr int GROUPS = 64 / LPE;   // edges per wave gather (8 or 16)
  constexpr int BH     = 32 / GROUPS; // batches per half-chunk (4 or 2)

  int node = blockIdx.x * 4 + (threadIdx.x >> 6);
  int lane = threadIdx.x & 63;
  if (node >= N_NODES) return;
  int bg = beg[node], end = bg + cnt[node];
  int g  = lane / LPE;               // which edge of the batch
  int f8 = lane % LPE;               // which feature octet

  float a0=0.f,a1=0.f,a2=0.f,a3=0.f,a4=0.f,a5=0.f,a6=0.f,a7=0.f;

  for (int p = bg; p < end; p += 64) {
    int q64 = p + lane;
    int idx = csr4[(q64 < end) ? q64 : (end - 1)];   // one coalesced load / chunk
#pragma unroll
    for (int half = 0; half < 2; half++) {
      if (half == 1 && p + 32 >= end) break;
      int   sarr[BH]; u16x8 harr[BH];
#pragma unroll
      for (int b = 0; b < BH; b++) {
        int e = (half * BH + b) * GROUPS + g;
        int s = __shfl(idx, e, 64);
        sarr[b] = (p + e < end) ? s : N_NODES;       // zero row when masked
      }
#pragma unroll
      for (int b = 0; b < BH; b++)
        harr[b] = *(const u16x8*)(H16 + (size_t)sarr[b] * FEAT + f8 * 8);
#pragma unroll
      for (int b = 0; b < BH; b++) {
        u16x8 h = harr[b];
        a0 += bf2f(h[0]); a1 += bf2f(h[1]);
        a2 += bf2f(h[2]); a3 += bf2f(h[3]);
        a4 += bf2f(h[4]); a5 += bf2f(h[5]);
        a6 += bf2f(h[6]); a7 += bf2f(h[7]);
      }
    }
  }

  // fold edge-groups together (g lives in the upper lane bits)
#pragma unroll
  for (int off = LPE; off < 64; off <<= 1) {
    a0 += __shfl_xor(a0, off, 64);
    a1 += __shfl_xor(a1, off, 64);
    a2 += __shfl_xor(a2, off, 64);
    a3 += __shfl_xor(a3, off, 64);
    a4 += __shfl_xor(a4, off, 64);
    a5 += __shfl_xor(a5, off, 64);
    a6 += __shfl_xor(a6, off, 64);
    a7 += __shfl_xor(a7, off, 64);
  }

  if (g == 0) {
    float di = dinv[node];
    u16x8 hs = *(const u16x8*)(H16 + (size_t)node * FEAT + f8 * 8);
    float4 bv0 = *(const float4*)(bias + f8 * 8);
    float4 bv1 = *(const float4*)(bias + f8 * 8 + 4);
    a0 = (a0 + bf2f(hs[0])) * di + bv0.x;
    a1 = (a1 + bf2f(hs[1])) * di + bv0.y;
    a2 = (a2 + bf2f(hs[2])) * di + bv0.z;
    a3 = (a3 + bf2f(hs[3])) * di + bv0.w;
    a4 = (a4 + bf2f(hs[4])) * di + bv1.x;
    a5 = (a5 + bf2f(hs[5])) * di + bv1.y;
    a6 = (a6 + bf2f(hs[6])) * di + bv1.z;
    a7 = (a7 + bf2f(hs[7])) * di + bv1.w;
    if (RELU) {
      a0 = fmaxf(a0, 0.f); a1 = fmaxf(a1, 0.f);
      a2 = fmaxf(a2, 0.f); a3 = fmaxf(a3, 0.f);
      a4 = fmaxf(a4, 0.f); a5 = fmaxf(a5, 0.f);
      a6 = fmaxf(a6, 0.f); a7 = fmaxf(a7, 0.f);
    }
    float4 o0; o0.x = a0; o0.y = a1; o0.z = a2; o0.w = a3;
    float4 o1; o1.x = a4; o1.y = a5; o1.z = a6; o1.w = a7;
    *(float4*)(OUT + (size_t)node * FEAT + f8 * 8)     = o0;
    *(float4*)(OUT + (size_t)node * FEAT + f8 * 8 + 4) = o1;
  }
}

// ---------------- decoder: fused 2-stage MFMA ----------------

__global__ __launch_bounds__(256) void k_decoder_mfma(
    const float* __restrict__ Z,
    const unsigned short* __restrict__ B1hi, const unsigned short* __restrict__ B1lo,
    const float* __restrict__ bd1,
    const unsigned short* __restrict__ B2hi, const unsigned short* __restrict__ B2lo,
    const float* __restrict__ bd2, float* __restrict__ RECON) {
  constexpr int KP1 = 40;   // 32+8
  constexpr int KP2 = 72;   // 64+8
  __shared__ __align__(16) unsigned short Azhi[64 * KP1];
  __shared__ __align__(16) unsigned short Azlo[64 * KP1];
  __shared__ __align__(16) unsigned short H3hi[64 * KP2];
  __shared__ __align__(16) unsigned short H3lo[64 * KP2];
  int t = threadIdx.x;
  int node0 = blockIdx.x * 64;

  for (int i = t; i < 512; i += 256) {
    int n = i >> 3, f4 = i & 7;
    float4 v = make_float4(0.f, 0.f, 0.f, 0.f);
    if (node0 + n < N_NODES) v = ((const float4*)(Z + (size_t)(node0 + n) * 32))[f4];
    int base = n * KP1 + f4 * 4;
    float vv[4] = {v.x, v.y, v.z, v.w};
#pragma unroll
    for (int j = 0; j < 4; j++) {
      unsigned short h = f2bf(vv[j]);
      Azhi[base + j] = h;
      Azlo[base + j] = f2bf(vv[j] - bf2f(h));
    }
  }
  __syncthreads();

  int w = t >> 6, lane = t & 63;
  int quad = lane >> 4, r16 = lane & 15;

  {
    int col = w * 16 + r16;
    float bias1 = bd1[col];
    bf16x8 bh = *(const bf16x8*)(B1hi + col * KP1 + quad * 8);
    bf16x8 bl = *(const bf16x8*)(B1lo + col * KP1 + quad * 8);
#pragma unroll
    for (int m = 0; m < 4; m++) {
      bf16x8 ah = *(const bf16x8*)(Azhi + (m * 16 + r16) * KP1 + quad * 8);
      bf16x8 al = *(const bf16x8*)(Azlo + (m * 16 + r16) * KP1 + quad * 8);
      f32x4 acc = {0.f, 0.f, 0.f, 0.f};
      acc = __builtin_amdgcn_mfma_f32_16x16x32_bf16(ah, bh, acc, 0, 0, 0);
      acc = __builtin_amdgcn_mfma_f32_16x16x32_bf16(ah, bl, acc, 0, 0, 0);
      acc = __builtin_amdgcn_mfma_f32_16x16x32_bf16(al, bh, acc, 0, 0, 0);
#pragma unroll
      for (int r = 0; r < 4; r++) {
        int row = m * 16 + quad * 4 + r;
        float hv = fmaxf(acc[r] + bias1, 0.f);
        unsigned short h = f2bf(hv);
        H3hi[row * KP2 + col] = h;
        H3lo[row * KP2 + col] = f2bf(hv - bf2f(h));
      }
    }
  }
  __syncthreads();

#pragma unroll
  for (int sp = 0; sp < 2; sp++) {
    int strip = w + sp * 4;
    int col = strip * 16 + r16;
    float bias2 = bd2[col];
    const unsigned short* b2h = B2hi + col * KP2 + quad * 8;
    const unsigned short* b2l = B2lo + col * KP2 + quad * 8;
    bf16x8 bh0 = *(const bf16x8*)(b2h);
    bf16x8 bh1 = *(const bf16x8*)(b2h + 32);
    bf16x8 bl0 = *(const bf16x8*)(b2l);
    bf16x8 bl1 = *(const bf16x8*)(b2l + 32);
#pragma unroll
    for (int m = 0; m < 4; m++) {
      const unsigned short* ahp = H3hi + (m * 16 + r16) * KP2 + quad * 8;
      const unsigned short* alp = H3lo + (m * 16 + r16) * KP2 + quad * 8;
      bf16x8 ah0 = *(const bf16x8*)(ahp);
      bf16x8 ah1 = *(const bf16x8*)(ahp + 32);
      bf16x8 al0 = *(const bf16x8*)(alp);
      bf16x8 al1 = *(const bf16x8*)(alp + 32);
      f32x4 acc = {0.f, 0.f, 0.f, 0.f};
      acc = __builtin_amdgcn_mfma_f32_16x16x32_bf16(ah0, bh0, acc, 0, 0, 0);
      acc = __builtin_amdgcn_mfma_f32_16x16x32_bf16(ah1, bh1, acc, 0, 0, 0);
      acc = __builtin_amdgcn_mfma_f32_16x16x32_bf16(ah0, bl0, acc, 0, 0, 0);
      acc = __builtin_amdgcn_mfma_f32_16x16x32_bf16(ah1, bl1, acc, 0, 0, 0);
      acc = __builtin_amdgcn_mfma_f32_16x16x32_bf16(al0, bh0, acc, 0, 0, 0);
      acc = __builtin_amdgcn_mfma_f32_16x16x32_bf16(al1, bh1, acc, 0, 0, 0);
#pragma unroll
      for (int r = 0; r < 4; r++) {
        int n = node0 + m * 16 + quad * 4 + r;
        if (n < N_NODES) RECON[(size_t)n * 128 + col] = acc[r] + bias2;
      }
    }
  }
}

// ---------------- launch ----------------

extern "C" void kernel_launch(void* const* d_in, const int* in_sizes, int n_in,
                              void* d_out, int out_size, void* d_ws, size_t ws_size,
                              hipStream_t stream) {
  const float* x    = (const float*)d_in[0];
  const int*   eidx = (const int*)d_in[1];
  const int*   esrc = eidx;
  const int*   edst = eidx + N_EDGES;
  const float* W1  = (const float*)d_in[2];
  const float* b1  = (const float*)d_in[3];
  const float* W2  = (const float*)d_in[4];
  const float* b2  = (const float*)d_in[5];
  const float* Wd1 = (const float*)d_in[6];
  const float* bd1 = (const float*)d_in[7];
  const float* Wd2 = (const float*)d_in[8];
  const float* bd2 = (const float*)d_in[9];

  float* recon = (float*)d_out;                                  // [N,128]
  float* z     = (float*)d_out + (size_t)N_NODES * D_INF;        // [N,32]
  // Scratch in the dead recon region (51.2 MB, written only by k_decoder_mfma):
  //   stage [196*10240] int @ +0     (8.03 MB)  -- dead after k_csr, reused:
  //   h1_16 [(N+1),64] bf16 @ +0       (12.80 MB, incl zero row)
  //   z1    [N,64] fp32 @ +12,800,512  (25.6 MB)
  //   h2_16 [(N+1),32] bf16 @ +38,401,024 (6.40 MB) -> ends 44.80 MB < 51.2 MB
  int*            stage = (int*)recon;
  unsigned short* h1_16 = (unsigned short*)recon;
  float*          z1    = (float*)((char*)recon + 12800512);
  unsigned short* h2_16 = (unsigned short*)((char*)recon + 38401024);

  char* ws = (char*)d_ws;
  int*   beg    = (int*)(ws + 0);              // 409,600
  int*   cntn   = (int*)(ws + 409600);         // 409,600
  float* dinv   = (float*)(ws + 819200);       // 409,600
  int*   bkcnt  = (int*)(ws + 1228800);        // 1,024
  int*   csr4   = (int*)(ws + 1229824);        // 8,028,160 (196*10240*4)
  unsigned short* w1hi  = (unsigned short*)(ws + 9257984);   // 17,408
  unsigned short* w1lo  = (unsigned short*)(ws + 9275392);   // 17,408
  unsigned short* w2hi  = (unsigned short*)(ws + 9292800);   //  4,608
  unsigned short* w2lo  = (unsigned short*)(ws + 9297408);   //  4,608
  unsigned short* wd1hi = (unsigned short*)(ws + 9302016);   //  5,120
  unsigned short* wd1lo = (unsigned short*)(ws + 9307136);   //  5,120
  unsigned short* wd2hi = (unsigned short*)(ws + 9312256);   // 18,432
  unsigned short* wd2lo = (unsigned short*)(ws + 9330688);   // 18,432
  // total ws use: 9,349,120 B

  k_prep_w<<<5, 256, 0, stream>>>(W1, W2, Wd1, Wd2, w1hi, w1lo, w2hi, w2lo,
                                  wd1hi, wd1lo, wd2hi, wd2lo, bkcnt);
  k_binA<<<ABLOCKS, 256, 0, stream>>>(esrc, edst, bkcnt, stage);
  k_csr<<<NBKT, 1024, 0, stream>>>(stage, bkcnt, beg, cntn, dinv, csr4);

  // h1' = (x @ W1) * dinv  (bf16, + zero row)  -- overwrites stage
  k_mfma_gemm<64, 128, 64><<<(N_NODES + 63) / 64, 256, 0, stream>>>(x, w1hi, w1lo, dinv, h1_16);
  // z1 = relu(dinv*(sum h1' + self) + b1)  (fp32 out)
  k_aggregate<64, true><<<(N_NODES + 3) / 4, 256, 0, stream>>>(h1_16, beg, cntn, csr4, dinv, b1, z1);
  // h2' = (z1 @ W2) * dinv  (bf16, + zero row)
  k_mfma_gemm<64, 64, 32><<<(N_NODES + 63) / 64, 256, 0, stream>>>(z1, w2hi, w2lo, dinv, h2_16);
  // z = dinv*(sum h2' + self) + b2  (latent output, fp32)
  k_aggregate<32, false><<<(N_NODES + 3) / 4, 256, 0, stream>>>(h2_16, beg, cntn, csr4, dinv, b2, z);
  // recon = relu(z@Wd1+bd1) @ Wd2 + bd2
  k_decoder_mfma<<<(N_NODES + 63) / 64, 256, 0, stream>>>(z, wd1hi, wd1lo, bd1,
                                                          wd2hi, wd2lo, bd2, recon);
}

// Round 12
// 290.157 us; speedup vs baseline: 1.1256x; 1.0094x over previous
//
#include <hip/hip_runtime.h>
#include <stdint.h>

#define N_NODES 100000
#define N_EDGES 1600000
#define D_INF   128
#define D_HID   64
#define D_LAT   32

typedef __attribute__((ext_vector_type(8))) short bf16x8;
typedef __attribute__((ext_vector_type(4))) float f32x4;
typedef __attribute__((ext_vector_type(8))) unsigned short u16x8;

__device__ __forceinline__ unsigned short f2bf(float v) {
  union { float f; unsigned int u; } x; x.f = v;
  unsigned int u = x.u + 0x7FFF + ((x.u >> 16) & 1);   // RNE
  return (unsigned short)(u >> 16);
}
__device__ __forceinline__ float bf2f(unsigned short h) {
  union { unsigned int u; float f; } x; x.u = ((unsigned int)h) << 16;
  return x.f;
}

// ---------------- binned CSR build ----------------
// k_binA (EPB=2048): bins edges by dst>>9 into fixed-capacity bucket regions,
// PACKED as (src<<9)|dst_local. Tail blocks (>= ABLOCKS) do weight prep
// concurrently (independent work; weights consumed 2 launches later).
// k_csr (1024 thr, one block per bucket): LDS histogram + scan + scatter.

#define NBKT      196    // ceil(100000 / 512)
#define BKT_SHIFT 9      // 512 nodes per bucket
#define BKT_CAP   10240  // fixed region capacity (mean 8192, sigma ~90)
#define EPB       2048   // edges per pass-A block
#define ABLOCKS   782    // ceil(1600000 / 2048)

__global__ __launch_bounds__(256) void k_binA(const int* __restrict__ esrc,
                                              const int* __restrict__ edst,
                                              int* __restrict__ bkcnt,
                                              int* __restrict__ stage,
                                              const float* __restrict__ W1,
                                              const float* __restrict__ W2,
                                              const float* __restrict__ Wd1,
                                              const float* __restrict__ Wd2,
                                              unsigned short* __restrict__ w1hi,
                                              unsigned short* __restrict__ w1lo,
                                              unsigned short* __restrict__ w2hi,
                                              unsigned short* __restrict__ w2lo,
                                              unsigned short* __restrict__ wd1hi,
                                              unsigned short* __restrict__ wd1lo,
                                              unsigned short* __restrict__ wd2hi,
                                              unsigned short* __restrict__ wd2lo) {
  __shared__ int cnt[NBKT];
  __shared__ int sc[256];
  __shared__ int garel[NBKT];
  __shared__ int pos[NBKT];
  __shared__ __align__(16) int2 stg[EPB];   // 16 KB
  int t = threadIdx.x;

  if (blockIdx.x >= ABLOCKS) {              // weight-prep tail blocks
    const float* src; unsigned short *hi, *lo; int K, M;
    switch (blockIdx.x - ABLOCKS) {
      case 0:  src = W1;  hi = w1hi;  lo = w1lo;  K = 128; M = 64;  break;
      case 1:  src = W2;  hi = w2hi;  lo = w2lo;  K = 64;  M = 32;  break;
      case 2:  src = Wd1; hi = wd1hi; lo = wd1lo; K = 32;  M = 64;  break;
      default: src = Wd2; hi = wd2hi; lo = wd2lo; K = 64;  M = 128; break;
    }
    int KP = K + 8;
    for (int i = t; i < K * M; i += 256) {
      int k = i / M, c = i % M;
      float v = src[i];
      unsigned short h = f2bf(v);
      hi[c * KP + k] = h;
      lo[c * KP + k] = f2bf(v - bf2f(h));
    }
    return;                                 // never reaches binA barriers
  }

  int e0 = blockIdx.x * EPB;

  for (int i = t; i < NBKT; i += 256) cnt[i] = 0;
  __syncthreads();

  int ds[8], ss[8];
  const int4* s4 = (const int4*)esrc;
  const int4* d4 = (const int4*)edst;
#pragma unroll
  for (int i = 0; i < 2; i++) {
    int idx4 = (e0 >> 2) + i * 256 + t;
    int4 dd = make_int4(-1, -1, -1, -1);
    int4 sv = make_int4(0, 0, 0, 0);
    if (idx4 < N_EDGES / 4) { dd = d4[idx4]; sv = s4[idx4]; }
    ds[i*4+0] = dd.x; ds[i*4+1] = dd.y; ds[i*4+2] = dd.z; ds[i*4+3] = dd.w;
    ss[i*4+0] = sv.x; ss[i*4+1] = sv.y; ss[i*4+2] = sv.z; ss[i*4+3] = sv.w;
  }
#pragma unroll
  for (int j = 0; j < 8; j++)
    if (ds[j] >= 0) atomicAdd(&cnt[ds[j] >> BKT_SHIFT], 1);
  __syncthreads();

  int c = (t < NBKT) ? cnt[t] : 0;
  sc[t] = c;
  __syncthreads();
  int incl = c;
#pragma unroll
  for (int off = 1; off < 256; off <<= 1) {
    int x = (t >= off) ? sc[t - off] : 0;
    __syncthreads();
    incl += x;
    sc[t] = incl;
    __syncthreads();
  }
  if (t < NBKT) {
    int lb = incl - c;
    int gb = 0;
    if (c > 0) gb = t * BKT_CAP + atomicAdd(&bkcnt[t], c);
    garel[t] = gb - lb;
    pos[t]   = lb;
  }
  __syncthreads();

#pragma unroll
  for (int j = 0; j < 8; j++) {
    if (ds[j] >= 0) {
      int b  = ds[j] >> BKT_SHIFT;
      int lp = atomicAdd(&pos[b], 1);
      stg[lp] = make_int2(ss[j], ds[j]);
    }
  }
  __syncthreads();

  int nval = N_EDGES - e0; if (nval > EPB) nval = EPB;
  for (int i = t; i < nval; i += 256) {
    int2 e = stg[i];
    stage[garel[e.y >> BKT_SHIFT] + i] = (e.x << BKT_SHIFT) | (e.y & 511);
  }
}

// one block per bucket: histogram + scan + scatter, all bucket-local
__global__ __launch_bounds__(1024) void k_csr(const int* __restrict__ stage,
                                              const int* __restrict__ bkcnt,
                                              int* __restrict__ beg,
                                              int* __restrict__ cnt,
                                              float* __restrict__ dinv,
                                              int* __restrict__ csr4) {
  __shared__ int hist[512];
  __shared__ int scan[512];
  int b = blockIdx.x, t = threadIdx.x;
  if (t < 512) hist[t] = 0;
  __syncthreads();
  int n = bkcnt[b];
  int nlo = b << BKT_SHIFT;
  const int* reg = stage + (size_t)b * BKT_CAP;
  for (int i = t; i < n; i += 1024)
    atomicAdd(&hist[reg[i] & 511], 1);
  __syncthreads();
  int v = (t < 512) ? hist[t] : 0;
  if (t < 512) scan[t] = v;
  __syncthreads();
  int incl = v;
#pragma unroll
  for (int off = 1; off < 512; off <<= 1) {
    int x = (t >= off && t < 512) ? scan[t - off] : 0;
    __syncthreads();
    if (t < 512) { incl += x; scan[t] = incl; }
    __syncthreads();
  }
  if (t < 512) {
    int loc = incl - v;
    int node = nlo + t;
    if (node < N_NODES) {
      beg[node]  = b * BKT_CAP + loc;
      cnt[node]  = v;
      dinv[node] = rsqrtf((float)(v + 1));
    }
    scan[t] = loc;
  }
  __syncthreads();
  int* c4 = csr4 + (size_t)b * BKT_CAP;
  for (int i = t; i < n; i += 1024) {
    int e = reg[i];
    int slot = atomicAdd(&scan[e & 511], 1);
    c4[slot] = e >> BKT_SHIFT;
  }
}

// ---------------- MFMA GEMM: Y[N,M] = (X[N,K] @ W[K,M]) * dinv[n], bf16 out --------

template<int NODES, int K, int M>
__global__ __launch_bounds__(256) void k_mfma_gemm(const float* __restrict__ X,
                                                   const unsigned short* __restrict__ Bhi,
                                                   const unsigned short* __restrict__ Blo,
                                                   const float* __restrict__ dinv,
                                                   unsigned short* __restrict__ Y16) {
  constexpr int KP     = K + 8;
  constexpr int NSTRIP = M / 16;
  constexpr int KSTEPS = K / 32;
  constexpr int MTW    = (NODES / 16) * NSTRIP / 4;
  __shared__ __align__(16) unsigned short Ahi[NODES * KP];
  __shared__ __align__(16) unsigned short Alo[NODES * KP];

  int t = threadIdx.x;
  int node0 = blockIdx.x * NODES;

  for (int i = t; i < NODES * K / 4; i += 256) {
    int n = i / (K / 4), f4 = i % (K / 4);
    float4 v = make_float4(0.f, 0.f, 0.f, 0.f);
    if (node0 + n < N_NODES) v = ((const float4*)(X + (size_t)(node0 + n) * K))[f4];
    int base = n * KP + f4 * 4;
    float vv[4] = {v.x, v.y, v.z, v.w};
#pragma unroll
    for (int j = 0; j < 4; j++) {
      unsigned short h = f2bf(vv[j]);
      Ahi[base + j] = h;
      Alo[base + j] = f2bf(vv[j] - bf2f(h));
    }
  }
  __syncthreads();

  int w = t >> 6, lane = t & 63;
  int quad = lane >> 4, r16 = lane & 15;
  int strip = w % NSTRIP;

  bf16x8 bh[KSTEPS], bl[KSTEPS];
  const unsigned short* bp = Bhi + (strip * 16 + r16) * KP + quad * 8;
  const unsigned short* bq = Blo + (strip * 16 + r16) * KP + quad * 8;
#pragma unroll
  for (int ks = 0; ks < KSTEPS; ks++) {
    bh[ks] = *(const bf16x8*)(bp + ks * 32);
    bl[ks] = *(const bf16x8*)(bq + ks * 32);
  }

#pragma unroll
  for (int c = 0; c < MTW; c++) {
    int mt = (w / NSTRIP) * MTW + c;
    f32x4 acc = {0.f, 0.f, 0.f, 0.f};
    const unsigned short* ap = &Ahi[(mt * 16 + r16) * KP + quad * 8];
    const unsigned short* aq = &Alo[(mt * 16 + r16) * KP + quad * 8];
#pragma unroll
    for (int ks = 0; ks < KSTEPS; ks++) {
      bf16x8 ah = *(const bf16x8*)(ap + ks * 32);
      bf16x8 al = *(const bf16x8*)(aq + ks * 32);
      acc = __builtin_amdgcn_mfma_f32_16x16x32_bf16(ah, bh[ks], acc, 0, 0, 0);
      acc = __builtin_amdgcn_mfma_f32_16x16x32_bf16(ah, bl[ks], acc, 0, 0, 0);
      acc = __builtin_amdgcn_mfma_f32_16x16x32_bf16(al, bh[ks], acc, 0, 0, 0);
    }
    int gn  = node0 + mt * 16 + quad * 4;
    int col = strip * 16 + r16;
#pragma unroll
    for (int r = 0; r < 4; r++) {
      if (gn + r < N_NODES)
        Y16[(size_t)(gn + r) * M + col] = f2bf(acc[r] * dinv[gn + r]);
    }
  }
}

// ---------------- aggregation (round-9 proven version: preloaded indices) ------
// One coalesced 64-lane csr4 load per 64-edge chunk; indices distributed via
// __shfl, so row gathers have no dependent index load in the chain.

template<int FEAT, bool RELU>
__global__ __launch_bounds__(256) void k_aggregate(const unsigned short* __restrict__ H16,
                            const int* __restrict__ beg,
                            const int* __restrict__ cnt,
                            const int* __restrict__ csr4,
                            const float* __restrict__ dinv, const float* __restrict__ bias,
                            float* __restrict__ OUT) {
  constexpr int LPE    = FEAT / 8;   // lanes per edge (8 or 4)
  constexpr int GROUPS = 64 / LPE;   // edges per wave gather (8 or 16)
  constexpr int BH     = 32 / GROUPS; // batches per half-chunk (4 or 2)

  int node = blockIdx.x * 4 + (threadIdx.x >> 6);
  int lane = threadIdx.x & 63;
  if (node >= N_NODES) return;
  int bg = beg[node], end = bg + cnt[node];
  int g  = lane / LPE;               // which edge of the batch
  int f8 = lane % LPE;               // which feature octet

  float a0=0.f,a1=0.f,a2=0.f,a3=0.f,a4=0.f,a5=0.f,a6=0.f,a7=0.f;

  for (int p = bg; p < end; p += 64) {
    int q64 = p + lane;
    int idx = csr4[(q64 < end) ? q64 : (end - 1)];   // one coalesced load / chunk
#pragma unroll
    for (int half = 0; half < 2; half++) {
      if (half == 1 && p + 32 >= end) break;
      int   sarr[BH]; float marr[BH]; u16x8 harr[BH];
#pragma unroll
      for (int b = 0; b < BH; b++) {
        int e = (half * BH + b) * GROUPS + g;
        int s = __shfl(idx, e, 64);
        bool v = (p + e < end);
        sarr[b] = v ? s : node;
        marr[b] = v ? 1.f : 0.f;
      }
#pragma unroll
      for (int b = 0; b < BH; b++)
        harr[b] = *(const u16x8*)(H16 + (size_t)sarr[b] * FEAT + f8 * 8);
#pragma unroll
      for (int b = 0; b < BH; b++) {
        float m = marr[b]; u16x8 h = harr[b];
        a0 += bf2f(h[0]) * m; a1 += bf2f(h[1]) * m;
        a2 += bf2f(h[2]) * m; a3 += bf2f(h[3]) * m;
        a4 += bf2f(h[4]) * m; a5 += bf2f(h[5]) * m;
        a6 += bf2f(h[6]) * m; a7 += bf2f(h[7]) * m;
      }
    }
  }

  // fold edge-groups together (g lives in the upper lane bits)
#pragma unroll
  for (int off = LPE; off < 64; off <<= 1) {
    a0 += __shfl_xor(a0, off, 64);
    a1 += __shfl_xor(a1, off, 64);
    a2 += __shfl_xor(a2, off, 64);
    a3 += __shfl_xor(a3, off, 64);
    a4 += __shfl_xor(a4, off, 64);
    a5 += __shfl_xor(a5, off, 64);
    a6 += __shfl_xor(a6, off, 64);
    a7 += __shfl_xor(a7, off, 64);
  }

  if (g == 0) {
    float di = dinv[node];
    u16x8 hs = *(const u16x8*)(H16 + (size_t)node * FEAT + f8 * 8);
    float4 bv0 = *(const float4*)(bias + f8 * 8);
    float4 bv1 = *(const float4*)(bias + f8 * 8 + 4);
    a0 = (a0 + bf2f(hs[0])) * di + bv0.x;
    a1 = (a1 + bf2f(hs[1])) * di + bv0.y;
    a2 = (a2 + bf2f(hs[2])) * di + bv0.z;
    a3 = (a3 + bf2f(hs[3])) * di + bv0.w;
    a4 = (a4 + bf2f(hs[4])) * di + bv1.x;
    a5 = (a5 + bf2f(hs[5])) * di + bv1.y;
    a6 = (a6 + bf2f(hs[6])) * di + bv1.z;
    a7 = (a7 + bf2f(hs[7])) * di + bv1.w;
    if (RELU) {
      a0 = fmaxf(a0, 0.f); a1 = fmaxf(a1, 0.f);
      a2 = fmaxf(a2, 0.f); a3 = fmaxf(a3, 0.f);
      a4 = fmaxf(a4, 0.f); a5 = fmaxf(a5, 0.f);
      a6 = fmaxf(a6, 0.f); a7 = fmaxf(a7, 0.f);
    }
    float4 o0; o0.x = a0; o0.y = a1; o0.z = a2; o0.w = a3;
    float4 o1; o1.x = a4; o1.y = a5; o1.z = a6; o1.w = a7;
    *(float4*)(OUT + (size_t)node * FEAT + f8 * 8)     = o0;
    *(float4*)(OUT + (size_t)node * FEAT + f8 * 8 + 4) = o1;
  }
}

// ---------------- decoder: fused 2-stage MFMA ----------------

__global__ __launch_bounds__(256) void k_decoder_mfma(
    const float* __restrict__ Z,
    const unsigned short* __restrict__ B1hi, const unsigned short* __restrict__ B1lo,
    const float* __restrict__ bd1,
    const unsigned short* __restrict__ B2hi, const unsigned short* __restrict__ B2lo,
    const float* __restrict__ bd2, float* __restrict__ RECON) {
  constexpr int KP1 = 40;   // 32+8
  constexpr int KP2 = 72;   // 64+8
  __shared__ __align__(16) unsigned short Azhi[64 * KP1];
  __shared__ __align__(16) unsigned short Azlo[64 * KP1];
  __shared__ __align__(16) unsigned short H3hi[64 * KP2];
  __shared__ __align__(16) unsigned short H3lo[64 * KP2];
  int t = threadIdx.x;
  int node0 = blockIdx.x * 64;

  for (int i = t; i < 512; i += 256) {
    int n = i >> 3, f4 = i & 7;
    float4 v = make_float4(0.f, 0.f, 0.f, 0.f);
    if (node0 + n < N_NODES) v = ((const float4*)(Z + (size_t)(node0 + n) * 32))[f4];
    int base = n * KP1 + f4 * 4;
    float vv[4] = {v.x, v.y, v.z, v.w};
#pragma unroll
    for (int j = 0; j < 4; j++) {
      unsigned short h = f2bf(vv[j]);
      Azhi[base + j] = h;
      Azlo[base + j] = f2bf(vv[j] - bf2f(h));
    }
  }
  __syncthreads();

  int w = t >> 6, lane = t & 63;
  int quad = lane >> 4, r16 = lane & 15;

  {
    int col = w * 16 + r16;
    float bias1 = bd1[col];
    bf16x8 bh = *(const bf16x8*)(B1hi + col * KP1 + quad * 8);
    bf16x8 bl = *(const bf16x8*)(B1lo + col * KP1 + quad * 8);
#pragma unroll
    for (int m = 0; m < 4; m++) {
      bf16x8 ah = *(const bf16x8*)(Azhi + (m * 16 + r16) * KP1 + quad * 8);
      bf16x8 al = *(const bf16x8*)(Azlo + (m * 16 + r16) * KP1 + quad * 8);
      f32x4 acc = {0.f, 0.f, 0.f, 0.f};
      acc = __builtin_amdgcn_mfma_f32_16x16x32_bf16(ah, bh, acc, 0, 0, 0);
      acc = __builtin_amdgcn_mfma_f32_16x16x32_bf16(ah, bl, acc, 0, 0, 0);
      acc = __builtin_amdgcn_mfma_f32_16x16x32_bf16(al, bh, acc, 0, 0, 0);
#pragma unroll
      for (int r = 0; r < 4; r++) {
        int row = m * 16 + quad * 4 + r;
        float hv = fmaxf(acc[r] + bias1, 0.f);
        unsigned short h = f2bf(hv);
        H3hi[row * KP2 + col] = h;
        H3lo[row * KP2 + col] = f2bf(hv - bf2f(h));
      }
    }
  }
  __syncthreads();

#pragma unroll
  for (int sp = 0; sp < 2; sp++) {
    int strip = w + sp * 4;
    int col = strip * 16 + r16;
    float bias2 = bd2[col];
    const unsigned short* b2h = B2hi + col * KP2 + quad * 8;
    const unsigned short* b2l = B2lo + col * KP2 + quad * 8;
    bf16x8 bh0 = *(const bf16x8*)(b2h);
    bf16x8 bh1 = *(const bf16x8*)(b2h + 32);
    bf16x8 bl0 = *(const bf16x8*)(b2l);
    bf16x8 bl1 = *(const bf16x8*)(b2l + 32);
#pragma unroll
    for (int m = 0; m < 4; m++) {
      const unsigned short* ahp = H3hi + (m * 16 + r16) * KP2 + quad * 8;
      const unsigned short* alp = H3lo + (m * 16 + r16) * KP2 + quad * 8;
      bf16x8 ah0 = *(const bf16x8*)(ahp);
      bf16x8 ah1 = *(const bf16x8*)(ahp + 32);
      bf16x8 al0 = *(const bf16x8*)(alp);
      bf16x8 al1 = *(const bf16x8*)(alp + 32);
      f32x4 acc = {0.f, 0.f, 0.f, 0.f};
      acc = __builtin_amdgcn_mfma_f32_16x16x32_bf16(ah0, bh0, acc, 0, 0, 0);
      acc = __builtin_amdgcn_mfma_f32_16x16x32_bf16(ah1, bh1, acc, 0, 0, 0);
      acc = __builtin_amdgcn_mfma_f32_16x16x32_bf16(ah0, bl0, acc, 0, 0, 0);
      acc = __builtin_amdgcn_mfma_f32_16x16x32_bf16(ah1, bl1, acc, 0, 0, 0);
      acc = __builtin_amdgcn_mfma_f32_16x16x32_bf16(al0, bh0, acc, 0, 0, 0);
      acc = __builtin_amdgcn_mfma_f32_16x16x32_bf16(al1, bh1, acc, 0, 0, 0);
#pragma unroll
      for (int r = 0; r < 4; r++) {
        int n = node0 + m * 16 + quad * 4 + r;
        if (n < N_NODES) RECON[(size_t)n * 128 + col] = acc[r] + bias2;
      }
    }
  }
}

// ---------------- launch ----------------

extern "C" void kernel_launch(void* const* d_in, const int* in_sizes, int n_in,
                              void* d_out, int out_size, void* d_ws, size_t ws_size,
                              hipStream_t stream) {
  const float* x    = (const float*)d_in[0];
  const int*   eidx = (const int*)d_in[1];
  const int*   esrc = eidx;
  const int*   edst = eidx + N_EDGES;
  const float* W1  = (const float*)d_in[2];
  const float* b1  = (const float*)d_in[3];
  const float* W2  = (const float*)d_in[4];
  const float* b2  = (const float*)d_in[5];
  const float* Wd1 = (const float*)d_in[6];
  const float* bd1 = (const float*)d_in[7];
  const float* Wd2 = (const float*)d_in[8];
  const float* bd2 = (const float*)d_in[9];

  float* recon = (float*)d_out;                                  // [N,128]
  float* z     = (float*)d_out + (size_t)N_NODES * D_INF;        // [N,32]
  // Scratch in the dead recon region (51.2 MB, written only by k_decoder_mfma):
  //   stage [196*10240] int @ +0     (8.03 MB)  -- dead after k_csr, reused:
  //   h1_16 [N,64] bf16 @ +0         (12.8 MB)
  //   z1    [N,64] fp32 @ +12.8 MB   (25.6 MB)
  //   h2_16 [N,32] bf16 @ +38.4 MB   ( 6.4 MB)   -> total 44.8 MB < 51.2 MB
  int*            stage = (int*)recon;
  unsigned short* h1_16 = (unsigned short*)recon;
  float*          z1    = (float*)((char*)recon + 12800000);
  unsigned short* h2_16 = (unsigned short*)((char*)recon + 38400000);

  char* ws = (char*)d_ws;
  int*   beg    = (int*)(ws + 0);              // 409,600
  int*   cntn   = (int*)(ws + 409600);         // 409,600
  float* dinv   = (float*)(ws + 819200);       // 409,600
  int*   bkcnt  = (int*)(ws + 1228800);        // 1,024
  int*   csr4   = (int*)(ws + 1229824);        // 8,028,160 (196*10240*4)
  unsigned short* w1hi  = (unsigned short*)(ws + 9257984);   // 17,408
  unsigned short* w1lo  = (unsigned short*)(ws + 9275392);   // 17,408
  unsigned short* w2hi  = (unsigned short*)(ws + 9292800);   //  4,608
  unsigned short* w2lo  = (unsigned short*)(ws + 9297408);   //  4,608
  unsigned short* wd1hi = (unsigned short*)(ws + 9302016);   //  5,120
  unsigned short* wd1lo = (unsigned short*)(ws + 9307136);   //  5,120
  unsigned short* wd2hi = (unsigned short*)(ws + 9312256);   // 18,432
  unsigned short* wd2lo = (unsigned short*)(ws + 9330688);   // 18,432
  // total ws use: 9,349,120 B

  hipMemsetAsync(bkcnt, 0, NBKT * sizeof(int), stream);
  // binA blocks [0, ABLOCKS) bin edges; tail blocks [ABLOCKS, ABLOCKS+4) prep weights
  k_binA<<<ABLOCKS + 4, 256, 0, stream>>>(esrc, edst, bkcnt, stage,
                                          W1, W2, Wd1, Wd2,
                                          w1hi, w1lo, w2hi, w2lo,
                                          wd1hi, wd1lo, wd2hi, wd2lo);
  k_csr<<<NBKT, 1024, 0, stream>>>(stage, bkcnt, beg, cntn, dinv, csr4);

  // h1' = (x @ W1) * dinv  (bf16)  -- overwrites stage (dead after k_csr)
  k_mfma_gemm<64, 128, 64><<<(N_NODES + 63) / 64, 256, 0, stream>>>(x, w1hi, w1lo, dinv, h1_16);
  // z1 = relu(dinv*(sum h1' + self) + b1)  (fp32 out)
  k_aggregate<64, true><<<(N_NODES + 3) / 4, 256, 0, stream>>>(h1_16, beg, cntn, csr4, dinv, b1, z1);
  // h2' = (z1 @ W2) * dinv  (bf16 out)
  k_mfma_gemm<64, 64, 32><<<(N_NODES + 63) / 64, 256, 0, stream>>>(z1, w2hi, w2lo, dinv, h2_16);
  // z = dinv*(sum h2' + self) + b2  (latent output, fp32)
  k_aggregate<32, false><<<(N_NODES + 3) / 4, 256, 0, stream>>>(h2_16, beg, cntn, csr4, dinv, b2, z);
  // recon = relu(z@Wd1+bd1) @ Wd2 + bd2
  k_decoder_mfma<<<(N_NODES + 63) / 64, 256, 0, stream>>>(z, wd1hi, wd1lo, bd1,
                                                          wd2hi, wd2lo, bd2, recon);
}